// Round 1
// baseline (2791.978 us; speedup 1.0000x reference)
//
#include <hip/hip_runtime.h>

typedef __attribute__((ext_vector_type(4))) float f32x4;
typedef __attribute__((ext_vector_type(8))) short short8;
typedef __attribute__((ext_vector_type(8))) __bf16 bf16x8;
typedef __attribute__((ext_vector_type(4))) unsigned short us4;

__device__ __forceinline__ unsigned short f2bf(float f) {
  unsigned u = __builtin_bit_cast(unsigned, f);
  u = (u + 0x7FFFu + ((u >> 16) & 1u)) >> 16;
  return (unsigned short)u;
}

__device__ __forceinline__ f32x4 mfma16(short8 a, short8 b, f32x4 c) {
  return __builtin_amdgcn_mfma_f32_16x16x32_bf16(
      __builtin_bit_cast(bf16x8, a), __builtin_bit_cast(bf16x8, b), c, 0, 0, 0);
}

// ---------------------------------------------------------------------------
// Cayley: Q = (I - A)^-1 (I + A), A = P - P^T.  One block per g (n=80 or 48).
// Gauss-Jordan with partial pivoting, fp32, all in LDS.
// ---------------------------------------------------------------------------
__launch_bounds__(256)
__global__ void cayley_kernel(const float* __restrict__ P, float* __restrict__ Qo, int n) {
  __shared__ float M[80 * 80];
  __shared__ float R[80 * 80];
  __shared__ float fcol[80];
  __shared__ int piv;
  int g = blockIdx.x, tid = threadIdx.x;
  const float* Pg = P + (size_t)g * n * n;
  for (int idx = tid; idx < n * n; idx += 256) {
    int i = idx / n, j = idx - i * n;
    float a = Pg[i * n + j] - Pg[j * n + i];
    float id = (i == j) ? 1.0f : 0.0f;
    M[idx] = id - a;
    R[idx] = id + a;
  }
  __syncthreads();
  int nch = n >> 2;
  for (int k = 0; k < n; ++k) {
    if (tid == 0) {
      int p = k; float best = fabsf(M[k * n + k]);
      for (int i = k + 1; i < n; ++i) {
        float v = fabsf(M[i * n + k]);
        if (v > best) { best = v; p = i; }
      }
      piv = p;
    }
    __syncthreads();
    int p = piv;
    if (p != k) {
      for (int j = tid; j < n; j += 256) {
        float tM = M[k * n + j]; M[k * n + j] = M[p * n + j]; M[p * n + j] = tM;
        float tR = R[k * n + j]; R[k * n + j] = R[p * n + j]; R[p * n + j] = tR;
      }
    }
    __syncthreads();
    float dk = M[k * n + k];
    __syncthreads();
    float inv = 1.0f / dk;
    for (int j = tid; j < n; j += 256) { M[k * n + j] *= inv; R[k * n + j] *= inv; }
    for (int i = tid; i < n; i += 256) fcol[i] = (i == k) ? 0.0f : M[i * n + k];
    __syncthreads();
    for (int idx = tid; idx < n * nch; idx += 256) {
      int i = idx / nch, c = idx - i * nch;
      if (i == k) continue;
      float f = fcol[i];
      f32x4* Mi = (f32x4*)&M[i * n]; const f32x4* Mk = (const f32x4*)&M[k * n];
      f32x4* Ri = (f32x4*)&R[i * n]; const f32x4* Rk = (const f32x4*)&R[k * n];
      Mi[c] = Mi[c] - f * Mk[c];
      Ri[c] = Ri[c] - f * Rk[c];
    }
    __syncthreads();
  }
  for (int idx = tid; idx < n * n; idx += 256) Qo[(size_t)g * n * n + idx] = R[idx];
}

// ---------------------------------------------------------------------------
// Fused effective weight: WeffT[o][k] = scale[o]*extra *
//   sum_m ( sum_j Qin[gi][i][j] * W[go*80+m][gi*b+j] ) * Qout[go][m][o%80]
// One block per (gi, go). fp32 compute, bf16 output, stored transposed [N][K].
// ---------------------------------------------------------------------------
__launch_bounds__(256)
__global__ void build_weight(const float* __restrict__ Qin, const float* __restrict__ W,
                             const float* __restrict__ Qout, const float* __restrict__ scale,
                             float extra, int b, int Kin, unsigned short* __restrict__ WeffT) {
  __shared__ float Qs[80 * 80];
  __shared__ float Ws[80 * 80];
  __shared__ float T1[80 * 80];
  __shared__ float QoT[80 * 80];
  int gi = blockIdx.x, go = blockIdx.y, tid = threadIdx.x;
  for (int idx = tid; idx < b * b; idx += 256) Qs[idx] = Qin[(size_t)gi * b * b + idx];
  for (int idx = tid; idx < 80 * b; idx += 256) {
    int m = idx / b, j = idx - m * b;
    Ws[idx] = W[(size_t)(go * 80 + m) * Kin + gi * b + j];
  }
  for (int idx = tid; idx < 80 * 80; idx += 256) {
    int m = idx / 80, n = idx - m * 80;
    QoT[n * 80 + m] = Qout[(size_t)go * 6400 + idx];
  }
  __syncthreads();
  int nch = b >> 2;
  for (int idx = tid; idx < b * 80; idx += 256) {
    int i = idx / 80, m = idx - i * 80;
    const f32x4* qa = (const f32x4*)&Qs[i * b];
    const f32x4* wb = (const f32x4*)&Ws[m * b];
    float s = 0.0f;
    for (int c = 0; c < nch; ++c) {
      f32x4 x = qa[c], y = wb[c];
      s += x[0] * y[0] + x[1] * y[1] + x[2] * y[2] + x[3] * y[3];
    }
    T1[i * 80 + m] = s;
  }
  __syncthreads();
  for (int idx = tid; idx < b * 80; idx += 256) {
    int i = idx / 80, n = idx - i * 80;
    const f32x4* ta = (const f32x4*)&T1[i * 80];
    const f32x4* qb = (const f32x4*)&QoT[n * 80];
    float s = 0.0f;
    for (int c = 0; c < 20; ++c) {
      f32x4 x = ta[c], y = qb[c];
      s += x[0] * y[0] + x[1] * y[1] + x[2] * y[2] + x[3] * y[3];
    }
    int col = go * 80 + n;
    float v = s * scale[col] * extra;
    WeffT[(size_t)col * Kin + gi * b + i] = f2bf(v);
  }
}

// ---------------------------------------------------------------------------
// fp32 -> bf16 bulk convert
// ---------------------------------------------------------------------------
__launch_bounds__(256)
__global__ void f32_to_bf16_kernel(const float* __restrict__ in, unsigned short* __restrict__ out,
                                   long long n) {
  long long i = ((long long)blockIdx.x * 256 + threadIdx.x) * 4;
  long long stride = (long long)gridDim.x * 256 * 4;
  for (; i < n; i += stride) {
    f32x4 v = *(const f32x4*)(in + i);
    us4 o;
    o[0] = f2bf(v[0]); o[1] = f2bf(v[1]); o[2] = f2bf(v[2]); o[3] = f2bf(v[3]);
    *(us4*)(out + i) = o;
  }
}

// ---------------------------------------------------------------------------
// bf16 MFMA GEMM: C[M,N] = A[M,K] @ Bt[N,K]^T.  128x128 tile, BK=32, 4 waves,
// each wave 64x64 via 4x4 fragments of mfma_f32_16x16x32_bf16.
// AF32: A is fp32 (convert during staging).  CF32: fp32 C (+bias).
// N % 128 == 0, K % 32 == 0, M guarded.
// ---------------------------------------------------------------------------
template <bool AF32, bool CF32, bool BIAS>
__launch_bounds__(256)
__global__ void gemm_kernel(const void* __restrict__ Ap, const unsigned short* __restrict__ Bt,
                            void* __restrict__ Cp, const float* __restrict__ bias,
                            int M, int N, int K) {
  __shared__ unsigned short As[128][40];  // stride 40 shorts = 80B (16B aligned, 2-way banks)
  __shared__ unsigned short Bs[128][40];  // Bs[n][k]
  int bn = blockIdx.x, bm = blockIdx.y;
  int tid = threadIdx.x;
  int l = tid & 63, wid = tid >> 6, lo = l & 15, hi = l >> 4;
  int wm = wid >> 1, wn = wid & 1;
  f32x4 z = {0.0f, 0.0f, 0.0f, 0.0f};
  f32x4 acc[4][4];
#pragma unroll
  for (int m = 0; m < 4; ++m)
#pragma unroll
    for (int n = 0; n < 4; ++n) acc[m][n] = z;
  int row0 = bm * 128;
  int ar = tid >> 2, acg = tid & 3;
  int bnr = tid >> 1, bhf = tid & 1;

  for (int k0 = 0; k0 < K; k0 += 32) {
    __syncthreads();
    // stage A (128x32), with M guard and optional fp32->bf16 convert
#pragma unroll
    for (int rr = 0; rr < 2; ++rr) {
      int row = ar + rr * 64;
      int grow = row0 + row;
      short8 v = {0, 0, 0, 0, 0, 0, 0, 0};
      if (AF32) {
        if (grow < M) {
          const float* ap = (const float*)Ap + (size_t)grow * K + k0 + acg * 8;
          f32x4 v0 = *(const f32x4*)ap;
          f32x4 v1 = *(const f32x4*)(ap + 4);
          v[0] = (short)f2bf(v0[0]); v[1] = (short)f2bf(v0[1]);
          v[2] = (short)f2bf(v0[2]); v[3] = (short)f2bf(v0[3]);
          v[4] = (short)f2bf(v1[0]); v[5] = (short)f2bf(v1[1]);
          v[6] = (short)f2bf(v1[2]); v[7] = (short)f2bf(v1[3]);
        }
      } else {
        if (grow < M)
          v = *(const short8*)((const unsigned short*)Ap + (size_t)grow * K + k0 + acg * 8);
      }
      *(short8*)&As[row][acg * 8] = v;
    }
    // stage B (128 rows of Bt, 32 k) — Bt is [N][K] so rows are contiguous
    {
      const unsigned short* bp = Bt + (size_t)(bn * 128 + bnr) * K + k0 + bhf * 16;
      *(short8*)&Bs[bnr][bhf * 16] = *(const short8*)bp;
      *(short8*)&Bs[bnr][bhf * 16 + 8] = *(const short8*)(bp + 8);
    }
    __syncthreads();
    short8 af[4], bf[4];
#pragma unroll
    for (int m = 0; m < 4; ++m) af[m] = *(const short8*)&As[wm * 64 + m * 16 + lo][hi * 8];
#pragma unroll
    for (int n = 0; n < 4; ++n) bf[n] = *(const short8*)&Bs[wn * 64 + n * 16 + lo][hi * 8];
#pragma unroll
    for (int m = 0; m < 4; ++m)
#pragma unroll
      for (int n = 0; n < 4; ++n) acc[m][n] = mfma16(af[m], bf[n], acc[m][n]);
  }

#pragma unroll
  for (int m = 0; m < 4; ++m)
#pragma unroll
    for (int n = 0; n < 4; ++n) {
      int col = bn * 128 + wn * 64 + n * 16 + lo;
#pragma unroll
      for (int j = 0; j < 4; ++j) {
        int row = row0 + wm * 64 + m * 16 + hi * 4 + j;
        if (row < M) {
          float v = acc[m][n][j];
          if (BIAS) v += bias[col];
          if (CF32) ((float*)Cp)[(size_t)row * N + col] = v;
          else ((unsigned short*)Cp)[(size_t)row * N + col] = f2bf(v);
        }
      }
    }
}

// ---------------------------------------------------------------------------
// Attention: Sk = 77 (single tile, no online softmax).  Grid (4096/64, 64 bh).
// Q pre-scaled (attn scale folded into Wq_eff).  QK^T and PV via MFMA.
// ---------------------------------------------------------------------------
#define QB 64
__launch_bounds__(256)
__global__ void attn_kernel(const unsigned short* __restrict__ Q,
                            const unsigned short* __restrict__ Kp,
                            const unsigned short* __restrict__ Vp,
                            unsigned short* __restrict__ O) {
  __shared__ unsigned short Qs[QB][168];   // 64 q rows x 160 d (pad->168)
  __shared__ unsigned short Ks[80][168];   // 80 t rows (77 real) x 160 d
  __shared__ unsigned short Vt[160][104];  // V transposed: d x t (96 used, pad->104)
  __shared__ unsigned short Ps[QB][104];   // probs: q rows x t (96 used)
  int tile = blockIdx.x, bh = blockIdx.y;
  int b = bh >> 3, h = bh & 7;
  int tid = threadIdx.x;

  const unsigned short* Qb = Q + (size_t)(b * 4096 + tile * QB) * 1280 + h * 160;
  for (int cid = tid; cid < QB * 20; cid += 256) {
    int r = cid / 20, c = cid - r * 20;
    *(short8*)&Qs[r][c * 8] = *(const short8*)&Qb[(size_t)r * 1280 + c * 8];
  }
  const unsigned short* Kb = Kp + (size_t)(b * 77) * 1280 + h * 160;
  for (int cid = tid; cid < 80 * 20; cid += 256) {
    int r = cid / 20, c = cid - r * 20;
    short8 v = {0, 0, 0, 0, 0, 0, 0, 0};
    if (r < 77) v = *(const short8*)&Kb[(size_t)r * 1280 + c * 8];
    *(short8*)&Ks[r][c * 8] = v;
  }
  const unsigned short* Vb = Vp + (size_t)(b * 77) * 1280 + h * 160;
  for (int cid = tid; cid < 77 * 20; cid += 256) {
    int t = cid / 20, c = cid - t * 20;
    short8 v = *(const short8*)&Vb[(size_t)t * 1280 + c * 8];
#pragma unroll
    for (int j = 0; j < 8; ++j) Vt[c * 8 + j][t] = (unsigned short)v[j];
  }
  for (int cid = tid; cid < 160 * 27; cid += 256) {
    int d = cid / 27, t = 77 + (cid - d * 27);
    Vt[d][t] = 0;
  }
  for (int cid = tid; cid < QB * 16; cid += 256) {
    int r = cid / 16, c = 80 + (cid & 15);
    Ps[r][c] = 0;
  }
  __syncthreads();

  int l = tid & 63, wid = tid >> 6, lo = l & 15, hi = l >> 4;
  // QK^T: wave handles 16 q rows, 5 n-tiles of 16 t
  f32x4 z = {0.0f, 0.0f, 0.0f, 0.0f};
  f32x4 sc[5];
#pragma unroll
  for (int n = 0; n < 5; ++n) sc[n] = z;
#pragma unroll
  for (int kt = 0; kt < 5; ++kt) {
    short8 a = *(const short8*)&Qs[wid * 16 + lo][kt * 32 + hi * 8];
#pragma unroll
    for (int n = 0; n < 5; ++n) {
      short8 bb = *(const short8*)&Ks[n * 16 + lo][kt * 32 + hi * 8];
      sc[n] = mfma16(a, bb, sc[n]);
    }
  }
  // mask pad cols (t = 64+lo >= 77)
  if (lo >= 13) { sc[4][0] = -1e30f; sc[4][1] = -1e30f; sc[4][2] = -1e30f; sc[4][3] = -1e30f; }
  // softmax per row (row = wid*16 + hi*4 + j; cols spread over lo and 5 regs)
  float pinv[4];
#pragma unroll
  for (int j = 0; j < 4; ++j) {
    float mx = sc[0][j];
#pragma unroll
    for (int n = 1; n < 5; ++n) mx = fmaxf(mx, sc[n][j]);
#pragma unroll
    for (int msk = 1; msk < 16; msk <<= 1) mx = fmaxf(mx, __shfl_xor(mx, msk, 64));
    float s = 0.0f;
#pragma unroll
    for (int n = 0; n < 5; ++n) {
      float p = __expf(sc[n][j] - mx);
      sc[n][j] = p;
      s += p;
    }
#pragma unroll
    for (int msk = 1; msk < 16; msk <<= 1) s += __shfl_xor(s, msk, 64);
    pinv[j] = 1.0f / s;
  }
#pragma unroll
  for (int n = 0; n < 5; ++n)
#pragma unroll
    for (int j = 0; j < 4; ++j)
      Ps[wid * 16 + hi * 4 + j][n * 16 + lo] = f2bf(sc[n][j] * pinv[j]);
  __syncthreads();

  // PV: out[16 rows][160 d], K-dim = 96 (padded probs/V are zero)
  f32x4 o[10];
#pragma unroll
  for (int n = 0; n < 10; ++n) o[n] = z;
#pragma unroll
  for (int kt = 0; kt < 3; ++kt) {
    short8 pa = *(const short8*)&Ps[wid * 16 + lo][kt * 32 + hi * 8];
#pragma unroll
    for (int n = 0; n < 10; ++n) {
      short8 vb = *(const short8*)&Vt[n * 16 + lo][kt * 32 + hi * 8];
      o[n] = mfma16(pa, vb, o[n]);
    }
  }
  unsigned short* Ob = O + (size_t)(b * 4096 + tile * QB + wid * 16 + hi * 4) * 1280 + h * 160;
#pragma unroll
  for (int n = 0; n < 10; ++n)
#pragma unroll
    for (int j = 0; j < 4; ++j)
      Ob[(size_t)j * 1280 + n * 16 + lo] = f2bf(o[n][j]);
}

// ---------------------------------------------------------------------------
extern "C" void kernel_launch(void* const* d_in, const int* in_sizes, int n_in,
                              void* d_out, int out_size, void* d_ws, size_t ws_size,
                              hipStream_t stream) {
  const float* hidden   = (const float*)d_in[0];
  const float* enc      = (const float*)d_in[1];
  const float* Pq_in    = (const float*)d_in[2];
  const float* Pk_in    = (const float*)d_in[3];
  const float* Pv_in    = (const float*)d_in[4];
  const float* Pout_in  = (const float*)d_in[5];
  const float* Pq_out   = (const float*)d_in[6];
  const float* Pk_out   = (const float*)d_in[7];
  const float* Pv_out   = (const float*)d_in[8];
  const float* Pout_out = (const float*)d_in[9];
  const float* Wq       = (const float*)d_in[10];
  const float* Wk       = (const float*)d_in[11];
  const float* Wv       = (const float*)d_in[12];
  const float* Wout     = (const float*)d_in[13];
  const float* bout     = (const float*)d_in[14];
  const float* q_scale  = (const float*)d_in[15];
  const float* k_scale  = (const float*)d_in[16];
  const float* v_scale  = (const float*)d_in[17];
  const float* out_scale= (const float*)d_in[18];

  char* w = (char*)d_ws;
  unsigned short* attnO = (unsigned short*)w; w += 32768LL * 1280 * 2;
  unsigned short* WqT   = (unsigned short*)w; w += 1280LL * 1280 * 2;
  unsigned short* WkT   = (unsigned short*)w; w += 1280LL * 768 * 2;
  unsigned short* WvT   = (unsigned short*)w; w += 1280LL * 768 * 2;
  unsigned short* WoT   = (unsigned short*)w; w += 1280LL * 1280 * 2;
  unsigned short* Kbf   = (unsigned short*)w; w += 616LL * 1280 * 2;
  unsigned short* Vbf   = (unsigned short*)w; w += 616LL * 1280 * 2;
  float* cQq_in   = (float*)w; w += 16LL * 80 * 80 * 4;
  float* cQout_in = (float*)w; w += 16LL * 80 * 80 * 4;
  float* cQq_out  = (float*)w; w += 16LL * 80 * 80 * 4;
  float* cQk_out  = (float*)w; w += 16LL * 80 * 80 * 4;
  float* cQv_out  = (float*)w; w += 16LL * 80 * 80 * 4;
  float* cQout_out= (float*)w; w += 16LL * 80 * 80 * 4;
  float* cQk_in   = (float*)w; w += 16LL * 48 * 48 * 4;
  float* cQv_in   = (float*)w; w += 16LL * 48 * 48 * 4;

  // d_out doubles as scratch: [Xbf | Qbf] in bf16; final GEMM overwrites with fp32.
  unsigned short* Xbf = (unsigned short*)d_out;
  unsigned short* Qbf = Xbf + 32768LL * 1280;

  cayley_kernel<<<16, 256, 0, stream>>>(Pq_in,   cQq_in,   80);
  cayley_kernel<<<16, 256, 0, stream>>>(Pk_in,   cQk_in,   48);
  cayley_kernel<<<16, 256, 0, stream>>>(Pv_in,   cQv_in,   48);
  cayley_kernel<<<16, 256, 0, stream>>>(Pout_in, cQout_in, 80);
  cayley_kernel<<<16, 256, 0, stream>>>(Pq_out,  cQq_out,  80);
  cayley_kernel<<<16, 256, 0, stream>>>(Pk_out,  cQk_out,  80);
  cayley_kernel<<<16, 256, 0, stream>>>(Pv_out,  cQv_out,  80);
  cayley_kernel<<<16, 256, 0, stream>>>(Pout_out,cQout_out,80);

  const float ATTN_SCALE = 0.07905694150420949f;  // 160^-0.5
  build_weight<<<dim3(16, 16), 256, 0, stream>>>(cQq_in,   Wq,   cQq_out,   q_scale,   ATTN_SCALE, 80, 1280, WqT);
  build_weight<<<dim3(16, 16), 256, 0, stream>>>(cQk_in,   Wk,   cQk_out,   k_scale,   1.0f,       48, 768,  WkT);
  build_weight<<<dim3(16, 16), 256, 0, stream>>>(cQv_in,   Wv,   cQv_out,   v_scale,   1.0f,       48, 768,  WvT);
  build_weight<<<dim3(16, 16), 256, 0, stream>>>(cQout_in, Wout, cQout_out, out_scale, 1.0f,       80, 1280, WoT);

  f32_to_bf16_kernel<<<2048, 256, 0, stream>>>(hidden, Xbf, 32768LL * 1280);

  // Q = Xbf @ WqT^T  (bf16 A path)
  gemm_kernel<false, false, false><<<dim3(10, 256), 256, 0, stream>>>(Xbf, WqT, Qbf, nullptr, 32768, 1280, 1280);
  // K,V projections from fp32 encoder states (M=616 guarded)
  gemm_kernel<true, false, false><<<dim3(10, 5), 256, 0, stream>>>(enc, WkT, Kbf, nullptr, 616, 1280, 768);
  gemm_kernel<true, false, false><<<dim3(10, 5), 256, 0, stream>>>(enc, WvT, Vbf, nullptr, 616, 1280, 768);

  attn_kernel<<<dim3(64, 64), 256, 0, stream>>>(Qbf, Kbf, Vbf, attnO);

  // final: fp32 out + bias
  gemm_kernel<false, true, true><<<dim3(10, 256), 256, 0, stream>>>(attnO, WoT, d_out, bout, 32768, 1280, 1280);
}

// Round 2
// 1036.263 us; speedup vs baseline: 2.6943x; 2.6943x over previous
//
#include <hip/hip_runtime.h>

typedef __attribute__((ext_vector_type(4))) float f32x4;
typedef __attribute__((ext_vector_type(8))) short short8;
typedef __attribute__((ext_vector_type(8))) __bf16 bf16x8;
typedef __attribute__((ext_vector_type(4))) unsigned short us4;

__device__ __forceinline__ unsigned short f2bf(float f) {
  unsigned u = __builtin_bit_cast(unsigned, f);
  u = (u + 0x7FFFu + ((u >> 16) & 1u)) >> 16;
  return (unsigned short)u;
}

__device__ __forceinline__ f32x4 mfma16(short8 a, short8 b, f32x4 c) {
  return __builtin_amdgcn_mfma_f32_16x16x32_bf16(
      __builtin_bit_cast(bf16x8, a), __builtin_bit_cast(bf16x8, b), c, 0, 0, 0);
}

// ---------------------------------------------------------------------------
// Fused Cayley for all 8 parameter tensors in ONE launch.
// Q = (I - A)^-1 (I + A), A = P - P^T.  Unpivoted Gauss-Jordan (valid: I-A has
// PD symmetric part -> nonsingular leading minors, pivots ~1).  Deferred row
// scaling: M stays unscaled (ends diagonal), R rows divided by diag at the end.
// 2 barriers per elimination step, no serial pivot search.
// Blocks 0..95: tensors 0..5 (n=80, 16 groups each); 96..127: tensors 6,7 (n=48).
// ---------------------------------------------------------------------------
struct CayleyPtrs {
  const float* P[8];
  float* Q[8];
};

__launch_bounds__(256)
__global__ void cayley_all(CayleyPtrs ptrs) {
  __shared__ float M[80 * 80];
  __shared__ float R[80 * 80];
  __shared__ float fcol[80];
  int t = blockIdx.x >> 4, g = blockIdx.x & 15;
  int n = (t < 6) ? 80 : 48;
  int tid = threadIdx.x;
  const float* Pg = ptrs.P[t] + (size_t)g * n * n;
  float* Qg = ptrs.Q[t] + (size_t)g * n * n;

  for (int idx = tid; idx < n * n; idx += 256) {
    int i = idx / n, j = idx - i * n;
    float a = Pg[i * n + j] - Pg[j * n + i];
    float id = (i == j) ? 1.0f : 0.0f;
    M[idx] = id - a;
    R[idx] = id + a;
  }
  __syncthreads();

  int nch = n >> 2;        // vec4 chunks per row
  int tot = n * nch;       // vec4 chunks per matrix
  for (int k = 0; k < n; ++k) {
    // phase 1: f[i] = M[i][k] / M[k][k]  (read-only on M; f[k]=0)
    if (tid < n) {
      float inv = 1.0f / M[k * n + k];
      fcol[tid] = (tid == k) ? 0.0f : M[tid * n + k] * inv;
    }
    __syncthreads();
    // phase 2: rank-1 update of both matrices, all rows (row k no-op via f=0)
    for (int idx = tid; idx < 2 * tot; idx += 256) {
      int isR = idx >= tot;
      int id2 = isR ? idx - tot : idx;
      int i = id2 / nch, c = id2 - i * nch;
      float f = fcol[i];
      f32x4* Xi = isR ? (f32x4*)&R[i * n] : (f32x4*)&M[i * n];
      const f32x4* Xk = isR ? (const f32x4*)&R[k * n] : (const f32x4*)&M[k * n];
      Xi[c] = Xi[c] - f * Xk[c];
    }
    __syncthreads();
  }
  // writeback: Q[i][j] = R[i][j] / M[i][i]
  for (int idx = tid; idx < n * n; idx += 256) {
    int i = idx / n;
    Qg[idx] = R[idx] / M[i * n + i];
  }
}

// ---------------------------------------------------------------------------
// Fused effective weight: WeffT[o][k] = scale[o]*extra *
//   sum_m ( sum_j Qin[gi][i][j] * W[go*80+m][gi*b+j] ) * Qout[go][m][o%80]
// One block per (gi, go). fp32 compute, bf16 output, stored transposed [N][K].
// ---------------------------------------------------------------------------
__launch_bounds__(256)
__global__ void build_weight(const float* __restrict__ Qin, const float* __restrict__ W,
                             const float* __restrict__ Qout, const float* __restrict__ scale,
                             float extra, int b, int Kin, unsigned short* __restrict__ WeffT) {
  __shared__ float Qs[80 * 80];
  __shared__ float Ws[80 * 80];
  __shared__ float T1[80 * 80];
  __shared__ float QoT[80 * 80];
  int gi = blockIdx.x, go = blockIdx.y, tid = threadIdx.x;
  for (int idx = tid; idx < b * b; idx += 256) Qs[idx] = Qin[(size_t)gi * b * b + idx];
  for (int idx = tid; idx < 80 * b; idx += 256) {
    int m = idx / b, j = idx - m * b;
    Ws[idx] = W[(size_t)(go * 80 + m) * Kin + gi * b + j];
  }
  for (int idx = tid; idx < 80 * 80; idx += 256) {
    int m = idx / 80, n = idx - m * 80;
    QoT[n * 80 + m] = Qout[(size_t)go * 6400 + idx];
  }
  __syncthreads();
  int nch = b >> 2;
  for (int idx = tid; idx < b * 80; idx += 256) {
    int i = idx / 80, m = idx - i * 80;
    const f32x4* qa = (const f32x4*)&Qs[i * b];
    const f32x4* wb = (const f32x4*)&Ws[m * b];
    float s = 0.0f;
    for (int c = 0; c < nch; ++c) {
      f32x4 x = qa[c], y = wb[c];
      s += x[0] * y[0] + x[1] * y[1] + x[2] * y[2] + x[3] * y[3];
    }
    T1[i * 80 + m] = s;
  }
  __syncthreads();
  for (int idx = tid; idx < b * 80; idx += 256) {
    int i = idx / 80, n = idx - i * 80;
    const f32x4* ta = (const f32x4*)&T1[i * 80];
    const f32x4* qb = (const f32x4*)&QoT[n * 80];
    float s = 0.0f;
    for (int c = 0; c < 20; ++c) {
      f32x4 x = ta[c], y = qb[c];
      s += x[0] * y[0] + x[1] * y[1] + x[2] * y[2] + x[3] * y[3];
    }
    int col = go * 80 + n;
    float v = s * scale[col] * extra;
    WeffT[(size_t)col * Kin + gi * b + i] = f2bf(v);
  }
}

// ---------------------------------------------------------------------------
// fp32 -> bf16 bulk convert
// ---------------------------------------------------------------------------
__launch_bounds__(256)
__global__ void f32_to_bf16_kernel(const float* __restrict__ in, unsigned short* __restrict__ out,
                                   long long n) {
  long long i = ((long long)blockIdx.x * 256 + threadIdx.x) * 4;
  long long stride = (long long)gridDim.x * 256 * 4;
  for (; i < n; i += stride) {
    f32x4 v = *(const f32x4*)(in + i);
    us4 o;
    o[0] = f2bf(v[0]); o[1] = f2bf(v[1]); o[2] = f2bf(v[2]); o[3] = f2bf(v[3]);
    *(us4*)(out + i) = o;
  }
}

// ---------------------------------------------------------------------------
// bf16 MFMA GEMM: C[M,N] = A[M,K] @ Bt[N,K]^T.  128x128 tile, BK=32, 4 waves,
// each wave 64x64 via 4x4 fragments of mfma_f32_16x16x32_bf16.
// AF32: A is fp32 (convert during staging).  CF32: fp32 C (+bias).
// N % 128 == 0, K % 32 == 0, M guarded.
// ---------------------------------------------------------------------------
template <bool AF32, bool CF32, bool BIAS>
__launch_bounds__(256)
__global__ void gemm_kernel(const void* __restrict__ Ap, const unsigned short* __restrict__ Bt,
                            void* __restrict__ Cp, const float* __restrict__ bias,
                            int M, int N, int K) {
  __shared__ unsigned short As[128][40];  // stride 40 shorts = 80B (16B aligned, 2-way banks)
  __shared__ unsigned short Bs[128][40];  // Bs[n][k]
  int bn = blockIdx.x, bm = blockIdx.y;
  int tid = threadIdx.x;
  int l = tid & 63, wid = tid >> 6, lo = l & 15, hi = l >> 4;
  int wm = wid >> 1, wn = wid & 1;
  f32x4 z = {0.0f, 0.0f, 0.0f, 0.0f};
  f32x4 acc[4][4];
#pragma unroll
  for (int m = 0; m < 4; ++m)
#pragma unroll
    for (int n = 0; n < 4; ++n) acc[m][n] = z;
  int row0 = bm * 128;
  int ar = tid >> 2, acg = tid & 3;
  int bnr = tid >> 1, bhf = tid & 1;

  for (int k0 = 0; k0 < K; k0 += 32) {
    __syncthreads();
    // stage A (128x32), with M guard and optional fp32->bf16 convert
#pragma unroll
    for (int rr = 0; rr < 2; ++rr) {
      int row = ar + rr * 64;
      int grow = row0 + row;
      short8 v = {0, 0, 0, 0, 0, 0, 0, 0};
      if (AF32) {
        if (grow < M) {
          const float* ap = (const float*)Ap + (size_t)grow * K + k0 + acg * 8;
          f32x4 v0 = *(const f32x4*)ap;
          f32x4 v1 = *(const f32x4*)(ap + 4);
          v[0] = (short)f2bf(v0[0]); v[1] = (short)f2bf(v0[1]);
          v[2] = (short)f2bf(v0[2]); v[3] = (short)f2bf(v0[3]);
          v[4] = (short)f2bf(v1[0]); v[5] = (short)f2bf(v1[1]);
          v[6] = (short)f2bf(v1[2]); v[7] = (short)f2bf(v1[3]);
        }
      } else {
        if (grow < M)
          v = *(const short8*)((const unsigned short*)Ap + (size_t)grow * K + k0 + acg * 8);
      }
      *(short8*)&As[row][acg * 8] = v;
    }
    // stage B (128 rows of Bt, 32 k) — Bt is [N][K] so rows are contiguous
    {
      const unsigned short* bp = Bt + (size_t)(bn * 128 + bnr) * K + k0 + bhf * 16;
      *(short8*)&Bs[bnr][bhf * 16] = *(const short8*)bp;
      *(short8*)&Bs[bnr][bhf * 16 + 8] = *(const short8*)(bp + 8);
    }
    __syncthreads();
    short8 af[4], bf[4];
#pragma unroll
    for (int m = 0; m < 4; ++m) af[m] = *(const short8*)&As[wm * 64 + m * 16 + lo][hi * 8];
#pragma unroll
    for (int n = 0; n < 4; ++n) bf[n] = *(const short8*)&Bs[wn * 64 + n * 16 + lo][hi * 8];
#pragma unroll
    for (int m = 0; m < 4; ++m)
#pragma unroll
      for (int n = 0; n < 4; ++n) acc[m][n] = mfma16(af[m], bf[n], acc[m][n]);
  }

#pragma unroll
  for (int m = 0; m < 4; ++m)
#pragma unroll
    for (int n = 0; n < 4; ++n) {
      int col = bn * 128 + wn * 64 + n * 16 + lo;
#pragma unroll
      for (int j = 0; j < 4; ++j) {
        int row = row0 + wm * 64 + m * 16 + hi * 4 + j;
        if (row < M) {
          float v = acc[m][n][j];
          if (BIAS) v += bias[col];
          if (CF32) ((float*)Cp)[(size_t)row * N + col] = v;
          else ((unsigned short*)Cp)[(size_t)row * N + col] = f2bf(v);
        }
      }
    }
}

// ---------------------------------------------------------------------------
// Attention: Sk = 77 (single tile, no online softmax).  Grid (4096/64, 64 bh).
// Q pre-scaled (attn scale folded into Wq_eff).  QK^T and PV via MFMA.
// ---------------------------------------------------------------------------
#define QB 64
__launch_bounds__(256)
__global__ void attn_kernel(const unsigned short* __restrict__ Q,
                            const unsigned short* __restrict__ Kp,
                            const unsigned short* __restrict__ Vp,
                            unsigned short* __restrict__ O) {
  __shared__ unsigned short Qs[QB][168];   // 64 q rows x 160 d (pad->168)
  __shared__ unsigned short Ks[80][168];   // 80 t rows (77 real) x 160 d
  __shared__ unsigned short Vt[160][104];  // V transposed: d x t (96 used, pad->104)
  __shared__ unsigned short Ps[QB][104];   // probs: q rows x t (96 used)
  int tile = blockIdx.x, bh = blockIdx.y;
  int b = bh >> 3, h = bh & 7;
  int tid = threadIdx.x;

  const unsigned short* Qb = Q + (size_t)(b * 4096 + tile * QB) * 1280 + h * 160;
  for (int cid = tid; cid < QB * 20; cid += 256) {
    int r = cid / 20, c = cid - r * 20;
    *(short8*)&Qs[r][c * 8] = *(const short8*)&Qb[(size_t)r * 1280 + c * 8];
  }
  const unsigned short* Kb = Kp + (size_t)(b * 77) * 1280 + h * 160;
  for (int cid = tid; cid < 80 * 20; cid += 256) {
    int r = cid / 20, c = cid - r * 20;
    short8 v = {0, 0, 0, 0, 0, 0, 0, 0};
    if (r < 77) v = *(const short8*)&Kb[(size_t)r * 1280 + c * 8];
    *(short8*)&Ks[r][c * 8] = v;
  }
  const unsigned short* Vb = Vp + (size_t)(b * 77) * 1280 + h * 160;
  for (int cid = tid; cid < 77 * 20; cid += 256) {
    int t = cid / 20, c = cid - t * 20;
    short8 v = *(const short8*)&Vb[(size_t)t * 1280 + c * 8];
#pragma unroll
    for (int j = 0; j < 8; ++j) Vt[c * 8 + j][t] = (unsigned short)v[j];
  }
  for (int cid = tid; cid < 160 * 27; cid += 256) {
    int d = cid / 27, t = 77 + (cid - d * 27);
    Vt[d][t] = 0;
  }
  for (int cid = tid; cid < QB * 16; cid += 256) {
    int r = cid / 16, c = 80 + (cid & 15);
    Ps[r][c] = 0;
  }
  __syncthreads();

  int l = tid & 63, wid = tid >> 6, lo = l & 15, hi = l >> 4;
  // QK^T: wave handles 16 q rows, 5 n-tiles of 16 t
  f32x4 z = {0.0f, 0.0f, 0.0f, 0.0f};
  f32x4 sc[5];
#pragma unroll
  for (int n = 0; n < 5; ++n) sc[n] = z;
#pragma unroll
  for (int kt = 0; kt < 5; ++kt) {
    short8 a = *(const short8*)&Qs[wid * 16 + lo][kt * 32 + hi * 8];
#pragma unroll
    for (int n = 0; n < 5; ++n) {
      short8 bb = *(const short8*)&Ks[n * 16 + lo][kt * 32 + hi * 8];
      sc[n] = mfma16(a, bb, sc[n]);
    }
  }
  // mask pad cols (t = 64+lo >= 77)
  if (lo >= 13) { sc[4][0] = -1e30f; sc[4][1] = -1e30f; sc[4][2] = -1e30f; sc[4][3] = -1e30f; }
  // softmax per row (row = wid*16 + hi*4 + j; cols spread over lo and 5 regs)
  float pinv[4];
#pragma unroll
  for (int j = 0; j < 4; ++j) {
    float mx = sc[0][j];
#pragma unroll
    for (int n = 1; n < 5; ++n) mx = fmaxf(mx, sc[n][j]);
#pragma unroll
    for (int msk = 1; msk < 16; msk <<= 1) mx = fmaxf(mx, __shfl_xor(mx, msk, 64));
    float s = 0.0f;
#pragma unroll
    for (int n = 0; n < 5; ++n) {
      float p = __expf(sc[n][j] - mx);
      sc[n][j] = p;
      s += p;
    }
#pragma unroll
    for (int msk = 1; msk < 16; msk <<= 1) s += __shfl_xor(s, msk, 64);
    pinv[j] = 1.0f / s;
  }
#pragma unroll
  for (int n = 0; n < 5; ++n)
#pragma unroll
    for (int j = 0; j < 4; ++j)
      Ps[wid * 16 + hi * 4 + j][n * 16 + lo] = f2bf(sc[n][j] * pinv[j]);
  __syncthreads();

  // PV: out[16 rows][160 d], K-dim = 96 (padded probs/V are zero)
  f32x4 o[10];
#pragma unroll
  for (int n = 0; n < 10; ++n) o[n] = z;
#pragma unroll
  for (int kt = 0; kt < 3; ++kt) {
    short8 pa = *(const short8*)&Ps[wid * 16 + lo][kt * 32 + hi * 8];
#pragma unroll
    for (int n = 0; n < 10; ++n) {
      short8 vb = *(const short8*)&Vt[n * 16 + lo][kt * 32 + hi * 8];
      o[n] = mfma16(pa, vb, o[n]);
    }
  }
  unsigned short* Ob = O + (size_t)(b * 4096 + tile * QB + wid * 16 + hi * 4) * 1280 + h * 160;
#pragma unroll
  for (int n = 0; n < 10; ++n)
#pragma unroll
    for (int j = 0; j < 4; ++j)
      Ob[(size_t)j * 1280 + n * 16 + lo] = f2bf(o[n][j]);
}

// ---------------------------------------------------------------------------
extern "C" void kernel_launch(void* const* d_in, const int* in_sizes, int n_in,
                              void* d_out, int out_size, void* d_ws, size_t ws_size,
                              hipStream_t stream) {
  const float* hidden   = (const float*)d_in[0];
  const float* enc      = (const float*)d_in[1];
  const float* Pq_in    = (const float*)d_in[2];
  const float* Pk_in    = (const float*)d_in[3];
  const float* Pv_in    = (const float*)d_in[4];
  const float* Pout_in  = (const float*)d_in[5];
  const float* Pq_out   = (const float*)d_in[6];
  const float* Pk_out   = (const float*)d_in[7];
  const float* Pv_out   = (const float*)d_in[8];
  const float* Pout_out = (const float*)d_in[9];
  const float* Wq       = (const float*)d_in[10];
  const float* Wk       = (const float*)d_in[11];
  const float* Wv       = (const float*)d_in[12];
  const float* Wout     = (const float*)d_in[13];
  const float* bout     = (const float*)d_in[14];
  const float* q_scale  = (const float*)d_in[15];
  const float* k_scale  = (const float*)d_in[16];
  const float* v_scale  = (const float*)d_in[17];
  const float* out_scale= (const float*)d_in[18];

  char* w = (char*)d_ws;
  unsigned short* attnO = (unsigned short*)w; w += 32768LL * 1280 * 2;
  unsigned short* WqT   = (unsigned short*)w; w += 1280LL * 1280 * 2;
  unsigned short* WkT   = (unsigned short*)w; w += 1280LL * 768 * 2;
  unsigned short* WvT   = (unsigned short*)w; w += 1280LL * 768 * 2;
  unsigned short* WoT   = (unsigned short*)w; w += 1280LL * 1280 * 2;
  unsigned short* Kbf   = (unsigned short*)w; w += 616LL * 1280 * 2;
  unsigned short* Vbf   = (unsigned short*)w; w += 616LL * 1280 * 2;
  float* cQq_in   = (float*)w; w += 16LL * 80 * 80 * 4;
  float* cQout_in = (float*)w; w += 16LL * 80 * 80 * 4;
  float* cQq_out  = (float*)w; w += 16LL * 80 * 80 * 4;
  float* cQk_out  = (float*)w; w += 16LL * 80 * 80 * 4;
  float* cQv_out  = (float*)w; w += 16LL * 80 * 80 * 4;
  float* cQout_out= (float*)w; w += 16LL * 80 * 80 * 4;
  float* cQk_in   = (float*)w; w += 16LL * 48 * 48 * 4;
  float* cQv_in   = (float*)w; w += 16LL * 48 * 48 * 4;

  // d_out doubles as scratch: [Xbf | Qbf] in bf16; final GEMM overwrites with fp32.
  unsigned short* Xbf = (unsigned short*)d_out;
  unsigned short* Qbf = Xbf + 32768LL * 1280;

  // one fused launch for all 8 Cayley transforms (128 blocks)
  CayleyPtrs cp;
  cp.P[0] = Pq_in;    cp.Q[0] = cQq_in;
  cp.P[1] = Pout_in;  cp.Q[1] = cQout_in;
  cp.P[2] = Pq_out;   cp.Q[2] = cQq_out;
  cp.P[3] = Pk_out;   cp.Q[3] = cQk_out;
  cp.P[4] = Pv_out;   cp.Q[4] = cQv_out;
  cp.P[5] = Pout_out; cp.Q[5] = cQout_out;
  cp.P[6] = Pk_in;    cp.Q[6] = cQk_in;
  cp.P[7] = Pv_in;    cp.Q[7] = cQv_in;
  cayley_all<<<128, 256, 0, stream>>>(cp);

  const float ATTN_SCALE = 0.07905694150420949f;  // 160^-0.5
  build_weight<<<dim3(16, 16), 256, 0, stream>>>(cQq_in,   Wq,   cQq_out,   q_scale,   ATTN_SCALE, 80, 1280, WqT);
  build_weight<<<dim3(16, 16), 256, 0, stream>>>(cQk_in,   Wk,   cQk_out,   k_scale,   1.0f,       48, 768,  WkT);
  build_weight<<<dim3(16, 16), 256, 0, stream>>>(cQv_in,   Wv,   cQv_out,   v_scale,   1.0f,       48, 768,  WvT);
  build_weight<<<dim3(16, 16), 256, 0, stream>>>(cQout_in, Wout, cQout_out, out_scale, 1.0f,       80, 1280, WoT);

  f32_to_bf16_kernel<<<2048, 256, 0, stream>>>(hidden, Xbf, 32768LL * 1280);

  // Q = Xbf @ WqT^T  (bf16 A path)
  gemm_kernel<false, false, false><<<dim3(10, 256), 256, 0, stream>>>(Xbf, WqT, Qbf, nullptr, 32768, 1280, 1280);
  // K,V projections from fp32 encoder states (M=616 guarded)
  gemm_kernel<true, false, false><<<dim3(10, 5), 256, 0, stream>>>(enc, WkT, Kbf, nullptr, 616, 1280, 768);
  gemm_kernel<true, false, false><<<dim3(10, 5), 256, 0, stream>>>(enc, WvT, Vbf, nullptr, 616, 1280, 768);

  attn_kernel<<<dim3(64, 64), 256, 0, stream>>>(Qbf, Kbf, Vbf, attnO);

  // final: fp32 out + bias
  gemm_kernel<false, true, true><<<dim3(10, 256), 256, 0, stream>>>(attnO, WoT, d_out, bout, 32768, 1280, 1280);
}

// Round 3
// 815.082 us; speedup vs baseline: 3.4254x; 1.2714x over previous
//
#include <hip/hip_runtime.h>

typedef __attribute__((ext_vector_type(4))) float f32x4;
typedef __attribute__((ext_vector_type(8))) short short8;
typedef __attribute__((ext_vector_type(8))) __bf16 bf16x8;
typedef __attribute__((ext_vector_type(4))) unsigned short us4;

__device__ __forceinline__ unsigned short f2bf(float f) {
  unsigned u = __builtin_bit_cast(unsigned, f);
  u = (u + 0x7FFFu + ((u >> 16) & 1u)) >> 16;
  return (unsigned short)u;
}

__device__ __forceinline__ f32x4 mfma16(short8 a, short8 b, f32x4 c) {
  return __builtin_amdgcn_mfma_f32_16x16x32_bf16(
      __builtin_bit_cast(bf16x8, a), __builtin_bit_cast(bf16x8, b), c, 0, 0, 0);
}

// async global->LDS, 16B per lane. LDS dest must be wave-uniform base; HW adds lane*16.
__device__ __forceinline__ void gload16(const unsigned short* g, unsigned short* l) {
  __builtin_amdgcn_global_load_lds((const __attribute__((address_space(1))) void*)g,
                                   (__attribute__((address_space(3))) void*)l, 16, 0, 0);
}

// ---------------------------------------------------------------------------
// Fused Cayley for all 8 parameter tensors in ONE launch (128 blocks).
// Unpivoted Gauss-Jordan, deferred row scaling. M updated only for cols >= k
// (earlier M columns are frozen zeros); R updated fully.
// ---------------------------------------------------------------------------
struct CayleyPtrs {
  const float* P[8];
  float* Q[8];
};

__launch_bounds__(256)
__global__ void cayley_all(CayleyPtrs ptrs) {
  __shared__ float M[80 * 80];
  __shared__ float R[80 * 80];
  __shared__ float fcol[80];
  int t = blockIdx.x >> 4, g = blockIdx.x & 15;
  int n = (t < 6) ? 80 : 48;
  int tid = threadIdx.x;
  const float* Pg = ptrs.P[t] + (size_t)g * n * n;
  float* Qg = ptrs.Q[t] + (size_t)g * n * n;

  for (int idx = tid; idx < n * n; idx += 256) {
    int i = idx / n, j = idx - i * n;
    float a = Pg[i * n + j] - Pg[j * n + i];
    float id = (i == j) ? 1.0f : 0.0f;
    M[idx] = id - a;
    R[idx] = id + a;
  }
  __syncthreads();

  int nch = n >> 2;
  int tot = n * nch;
  for (int k = 0; k < n; ++k) {
    if (tid < n) {
      float inv = 1.0f / M[k * n + k];
      fcol[tid] = (tid == k) ? 0.0f : M[tid * n + k] * inv;
    }
    __syncthreads();
    // R: full rank-1 update
    for (int idx = tid; idx < tot; idx += 256) {
      int i = idx / nch, c = idx - i * nch;
      float f = fcol[i];
      ((f32x4*)&R[i * n])[c] = ((f32x4*)&R[i * n])[c] - f * ((const f32x4*)&R[k * n])[c];
    }
    // M: only chunks containing cols >= k
    int c0 = k >> 2, mw = nch - c0, totM = n * mw;
    for (int idx = tid; idx < totM; idx += 256) {
      int i = idx / mw, c = c0 + idx - i * mw;
      float f = fcol[i];
      ((f32x4*)&M[i * n])[c] = ((f32x4*)&M[i * n])[c] - f * ((const f32x4*)&M[k * n])[c];
    }
    __syncthreads();
  }
  for (int idx = tid; idx < n * n; idx += 256) {
    int i = idx / n;
    Qg[idx] = R[idx] / M[i * n + i];
  }
}

// ---------------------------------------------------------------------------
// Fused effective weights, all 4 tensors in one launch: grid (16,16,4).
// WeffT[o][k] = scale[o]*extra * sum_m (sum_j Qin[gi][i][j]*W[go*80+m][gi*b+j]) * Qout[go][m][o%80]
// ---------------------------------------------------------------------------
struct BuildArgs {
  const float* Qin[4];
  const float* W[4];
  const float* Qout[4];
  const float* scale[4];
  unsigned short* WeffT[4];
  float extra[4];
  int b[4];
  int Kin[4];
};

__launch_bounds__(256)
__global__ void build_all(BuildArgs A) {
  __shared__ float Qs[80 * 80];
  __shared__ float Ws[80 * 80];
  __shared__ float T1[80 * 80];
  __shared__ float QoT[80 * 80];
  int z = blockIdx.z;
  int gi = blockIdx.x, go = blockIdx.y, tid = threadIdx.x;
  int b = A.b[z], Kin = A.Kin[z];
  float extra = A.extra[z];
  const float* Qin = A.Qin[z];
  const float* W = A.W[z];
  const float* Qout = A.Qout[z];
  const float* scale = A.scale[z];
  unsigned short* WeffT = A.WeffT[z];

  for (int idx = tid; idx < b * b; idx += 256) Qs[idx] = Qin[(size_t)gi * b * b + idx];
  for (int idx = tid; idx < 80 * b; idx += 256) {
    int m = idx / b, j = idx - m * b;
    Ws[idx] = W[(size_t)(go * 80 + m) * Kin + gi * b + j];
  }
  for (int idx = tid; idx < 80 * 80; idx += 256) {
    int m = idx / 80, n = idx - m * 80;
    QoT[n * 80 + m] = Qout[(size_t)go * 6400 + idx];
  }
  __syncthreads();
  int nch = b >> 2;
  for (int idx = tid; idx < b * 80; idx += 256) {
    int i = idx / 80, m = idx - i * 80;
    const f32x4* qa = (const f32x4*)&Qs[i * b];
    const f32x4* wb = (const f32x4*)&Ws[m * b];
    float s = 0.0f;
    for (int c = 0; c < nch; ++c) {
      f32x4 x = qa[c], y = wb[c];
      s += x[0] * y[0] + x[1] * y[1] + x[2] * y[2] + x[3] * y[3];
    }
    T1[i * 80 + m] = s;
  }
  __syncthreads();
  for (int idx = tid; idx < b * 80; idx += 256) {
    int i = idx / 80, n = idx - i * 80;
    const f32x4* ta = (const f32x4*)&T1[i * 80];
    const f32x4* qb = (const f32x4*)&QoT[n * 80];
    float s = 0.0f;
    for (int c = 0; c < 20; ++c) {
      f32x4 x = ta[c], y = qb[c];
      s += x[0] * y[0] + x[1] * y[1] + x[2] * y[2] + x[3] * y[3];
    }
    int col = go * 80 + n;
    float v = s * scale[col] * extra;
    WeffT[(size_t)col * Kin + gi * b + i] = f2bf(v);
  }
}

// ---------------------------------------------------------------------------
// fp32 -> bf16 bulk convert
// ---------------------------------------------------------------------------
__launch_bounds__(256)
__global__ void f32_to_bf16_kernel(const float* __restrict__ in, unsigned short* __restrict__ out,
                                   long long n) {
  long long i = ((long long)blockIdx.x * 256 + threadIdx.x) * 4;
  long long stride = (long long)gridDim.x * 256 * 4;
  for (; i < n; i += stride) {
    f32x4 v = *(const f32x4*)(in + i);
    us4 o;
    o[0] = f2bf(v[0]); o[1] = f2bf(v[1]); o[2] = f2bf(v[2]); o[3] = f2bf(v[3]);
    *(us4*)(out + i) = o;
  }
}

// ---------------------------------------------------------------------------
// m97-style bf16 MFMA GEMM: C[M,N] = A[M,K] @ Bt[N,K]^T.
// 128x128 tile, BK=32, 4 waves, linear LDS, global_load_lds width=16,
// XCD-aware bijective block swizzle (nwg % 8 == 0).
// Requires: M % 128 == 0, N % 128 == 0, K % 32 == 0, A/Bt 16B-aligned rows.
// ---------------------------------------------------------------------------
template <bool CF32, bool BIAS>
__launch_bounds__(256)
__global__ void gemm_lds(const unsigned short* __restrict__ A,
                         const unsigned short* __restrict__ Bt,
                         void* __restrict__ Cp, const float* __restrict__ bias,
                         int M, int N, int K) {
  __shared__ alignas(128) unsigned short As[128 * 32];
  __shared__ alignas(128) unsigned short Bs[128 * 32];
  int nwg = gridDim.x;
  int per = nwg >> 3;
  int bid = blockIdx.x;
  int nid = (bid & 7) * per + (bid >> 3);   // consecutive-on-XCD blocks share bm
  int nbn = N >> 7;
  int bm = nid / nbn, bn = nid - bm * nbn;

  int tid = threadIdx.x;
  int l = tid & 63, w = tid >> 6, lo = l & 15, hi = l >> 4;
  int wm = w >> 1, wn = w & 1;
  int row0 = bm * 128, col0 = bn * 128;

  // staging geometry: wave w covers rows [w*32, w*32+32) via two 16-row issues
  int srow = (l >> 2);        // 0..15 within issue
  int schk = (l & 3) * 8;     // k-offset in shorts
  const unsigned short* a0 = A + (size_t)(row0 + w * 32 + srow) * K + schk;
  const unsigned short* a1 = a0 + (size_t)16 * K;
  const unsigned short* b0 = Bt + (size_t)(col0 + w * 32 + srow) * K + schk;
  const unsigned short* b1 = b0 + (size_t)16 * K;
  unsigned short* lAs0 = &As[(w * 32) * 32];
  unsigned short* lAs1 = &As[(w * 32 + 16) * 32];
  unsigned short* lBs0 = &Bs[(w * 32) * 32];
  unsigned short* lBs1 = &Bs[(w * 32 + 16) * 32];

  f32x4 z = {0.0f, 0.0f, 0.0f, 0.0f};
  f32x4 acc[4][4];
#pragma unroll
  for (int m = 0; m < 4; ++m)
#pragma unroll
    for (int n = 0; n < 4; ++n) acc[m][n] = z;

  for (int k0 = 0; k0 < K; k0 += 32) {
    gload16(a0 + k0, lAs0);
    gload16(a1 + k0, lAs1);
    gload16(b0 + k0, lBs0);
    gload16(b1 + k0, lBs1);
    __syncthreads();   // compiler drains vmcnt before barrier -> LDS ready
    short8 af[4], bf[4];
#pragma unroll
    for (int m = 0; m < 4; ++m) af[m] = *(const short8*)&As[(wm * 64 + m * 16 + lo) * 32 + hi * 8];
#pragma unroll
    for (int n = 0; n < 4; ++n) bf[n] = *(const short8*)&Bs[(wn * 64 + n * 16 + lo) * 32 + hi * 8];
#pragma unroll
    for (int m = 0; m < 4; ++m)
#pragma unroll
      for (int n = 0; n < 4; ++n) acc[m][n] = mfma16(af[m], bf[n], acc[m][n]);
    __syncthreads();   // protect LDS before next stage
  }

#pragma unroll
  for (int m = 0; m < 4; ++m)
#pragma unroll
    for (int n = 0; n < 4; ++n) {
      int col = col0 + wn * 64 + n * 16 + lo;
#pragma unroll
      for (int j = 0; j < 4; ++j) {
        int row = row0 + wm * 64 + m * 16 + hi * 4 + j;
        float v = acc[m][n][j];
        if (BIAS) v += bias[col];
        if (CF32) ((float*)Cp)[(size_t)row * N + col] = v;
        else ((unsigned short*)Cp)[(size_t)row * N + col] = f2bf(v);
      }
    }
}

// ---------------------------------------------------------------------------
// reg-staged GEMM for small fp32-A cases (M guarded): K/V projections.
// ---------------------------------------------------------------------------
__launch_bounds__(256)
__global__ void gemm_small_f32a(const float* __restrict__ Ap, const unsigned short* __restrict__ Bt,
                                unsigned short* __restrict__ Cp, int M, int N, int K) {
  __shared__ unsigned short As[128][40];
  __shared__ unsigned short Bs[128][40];
  int bn = blockIdx.x, bm = blockIdx.y;
  int tid = threadIdx.x;
  int l = tid & 63, wid = tid >> 6, lo = l & 15, hi = l >> 4;
  int wm = wid >> 1, wn = wid & 1;
  f32x4 z = {0.0f, 0.0f, 0.0f, 0.0f};
  f32x4 acc[4][4];
#pragma unroll
  for (int m = 0; m < 4; ++m)
#pragma unroll
    for (int n = 0; n < 4; ++n) acc[m][n] = z;
  int row0 = bm * 128;
  int ar = tid >> 2, acg = tid & 3;
  int bnr = tid >> 1, bhf = tid & 1;

  for (int k0 = 0; k0 < K; k0 += 32) {
    __syncthreads();
#pragma unroll
    for (int rr = 0; rr < 2; ++rr) {
      int row = ar + rr * 64;
      int grow = row0 + row;
      short8 v = {0, 0, 0, 0, 0, 0, 0, 0};
      if (grow < M) {
        const float* ap = Ap + (size_t)grow * K + k0 + acg * 8;
        f32x4 v0 = *(const f32x4*)ap;
        f32x4 v1 = *(const f32x4*)(ap + 4);
        v[0] = (short)f2bf(v0[0]); v[1] = (short)f2bf(v0[1]);
        v[2] = (short)f2bf(v0[2]); v[3] = (short)f2bf(v0[3]);
        v[4] = (short)f2bf(v1[0]); v[5] = (short)f2bf(v1[1]);
        v[6] = (short)f2bf(v1[2]); v[7] = (short)f2bf(v1[3]);
      }
      *(short8*)&As[row][acg * 8] = v;
    }
    {
      const unsigned short* bp = Bt + (size_t)(bn * 128 + bnr) * K + k0 + bhf * 16;
      *(short8*)&Bs[bnr][bhf * 16] = *(const short8*)bp;
      *(short8*)&Bs[bnr][bhf * 16 + 8] = *(const short8*)(bp + 8);
    }
    __syncthreads();
    short8 af[4], bf[4];
#pragma unroll
    for (int m = 0; m < 4; ++m) af[m] = *(const short8*)&As[wm * 64 + m * 16 + lo][hi * 8];
#pragma unroll
    for (int n = 0; n < 4; ++n) bf[n] = *(const short8*)&Bs[wn * 64 + n * 16 + lo][hi * 8];
#pragma unroll
    for (int m = 0; m < 4; ++m)
#pragma unroll
      for (int n = 0; n < 4; ++n) acc[m][n] = mfma16(af[m], bf[n], acc[m][n]);
  }

#pragma unroll
  for (int m = 0; m < 4; ++m)
#pragma unroll
    for (int n = 0; n < 4; ++n) {
      int col = bn * 128 + wn * 64 + n * 16 + lo;
#pragma unroll
      for (int j = 0; j < 4; ++j) {
        int row = row0 + wm * 64 + m * 16 + hi * 4 + j;
        if (row < M) Cp[(size_t)row * N + col] = f2bf(acc[m][n][j]);
      }
    }
}

// ---------------------------------------------------------------------------
// Attention: Sk=77 single tile. Q/K read straight from global (K/V L2-fit,
// Common-mistake #7); only V (transposed) and P go through LDS -> 47KB, 1 barrier.
// ---------------------------------------------------------------------------
#define QB 64
__launch_bounds__(256)
__global__ void attn_kernel(const unsigned short* __restrict__ Q,
                            const unsigned short* __restrict__ Kp,
                            const unsigned short* __restrict__ Vp,
                            unsigned short* __restrict__ O) {
  __shared__ alignas(16) unsigned short Vt[160][104];  // V^T: d x t (96 used)
  __shared__ alignas(16) unsigned short Ps[QB][104];   // probs: q x t (96 used)
  int tile = blockIdx.x, bh = blockIdx.y;
  int b = bh >> 3, h = bh & 7;
  int tid = threadIdx.x;

  // stage V^T (+ zero pads), zero Ps pad cols
  const unsigned short* Vb = Vp + (size_t)(b * 77) * 1280 + h * 160;
  for (int cid = tid; cid < 77 * 20; cid += 256) {
    int t = cid / 20, c = cid - t * 20;
    short8 v = *(const short8*)&Vb[(size_t)t * 1280 + c * 8];
#pragma unroll
    for (int j = 0; j < 8; ++j) Vt[c * 8 + j][t] = (unsigned short)v[j];
  }
  for (int cid = tid; cid < 160 * 27; cid += 256) {
    int d = cid / 27, t = 77 + (cid - d * 27);
    Vt[d][t] = 0;
  }
  for (int cid = tid; cid < QB * 16; cid += 256) {
    int r = cid / 16, c = 80 + (cid & 15);
    Ps[r][c] = 0;
  }

  int l = tid & 63, wid = tid >> 6, lo = l & 15, hi = l >> 4;

  // QK^T straight from global: wave wid owns q-rows [wid*16, +16)
  const unsigned short* qrow =
      Q + (size_t)(b * 4096 + tile * QB + wid * 16 + lo) * 1280 + h * 160;
  short8 a[5];
#pragma unroll
  for (int kt = 0; kt < 5; ++kt) a[kt] = *(const short8*)&qrow[kt * 32 + hi * 8];

  const unsigned short* Kb = Kp + (size_t)(b * 77) * 1280 + h * 160;
  f32x4 z = {0.0f, 0.0f, 0.0f, 0.0f};
  f32x4 sc[5];
#pragma unroll
  for (int n = 0; n < 5; ++n) sc[n] = z;
#pragma unroll
  for (int n = 0; n < 5; ++n) {
    const unsigned short* krow = Kb + (size_t)(n * 16 + lo) * 1280;  // rows 77..79 garbage, masked below
#pragma unroll
    for (int kt = 0; kt < 5; ++kt) {
      short8 bb = *(const short8*)&krow[kt * 32 + hi * 8];
      sc[n] = mfma16(a[kt], bb, sc[n]);
    }
  }
  // mask pad cols t = 64+lo >= 77 (overwrite kills any garbage from rows 77..79)
  if (lo >= 13) { sc[4][0] = -1e30f; sc[4][1] = -1e30f; sc[4][2] = -1e30f; sc[4][3] = -1e30f; }

  float pinv[4];
#pragma unroll
  for (int j = 0; j < 4; ++j) {
    float mx = sc[0][j];
#pragma unroll
    for (int n = 1; n < 5; ++n) mx = fmaxf(mx, sc[n][j]);
#pragma unroll
    for (int msk = 1; msk < 16; msk <<= 1) mx = fmaxf(mx, __shfl_xor(mx, msk, 64));
    float s = 0.0f;
#pragma unroll
    for (int n = 0; n < 5; ++n) {
      float p = __expf(sc[n][j] - mx);
      sc[n][j] = p;
      s += p;
    }
#pragma unroll
    for (int msk = 1; msk < 16; msk <<= 1) s += __shfl_xor(s, msk, 64);
    pinv[j] = 1.0f / s;
  }
#pragma unroll
  for (int n = 0; n < 5; ++n)
#pragma unroll
    for (int j = 0; j < 4; ++j)
      Ps[wid * 16 + hi * 4 + j][n * 16 + lo] = f2bf(sc[n][j] * pinv[j]);
  __syncthreads();  // Vt + Ps ready

  // PV: out[16 rows][160 d], K-dim 96 (pads are zero)
  f32x4 o[10];
#pragma unroll
  for (int n = 0; n < 10; ++n) o[n] = z;
#pragma unroll
  for (int kt = 0; kt < 3; ++kt) {
    short8 pa = *(const short8*)&Ps[wid * 16 + lo][kt * 32 + hi * 8];
#pragma unroll
    for (int n = 0; n < 10; ++n) {
      short8 vb = *(const short8*)&Vt[n * 16 + lo][kt * 32 + hi * 8];
      o[n] = mfma16(pa, vb, o[n]);
    }
  }
  unsigned short* Ob = O + (size_t)(b * 4096 + tile * QB + wid * 16 + hi * 4) * 1280 + h * 160;
#pragma unroll
  for (int n = 0; n < 10; ++n)
#pragma unroll
    for (int j = 0; j < 4; ++j)
      Ob[(size_t)j * 1280 + n * 16 + lo] = f2bf(o[n][j]);
}

// ---------------------------------------------------------------------------
extern "C" void kernel_launch(void* const* d_in, const int* in_sizes, int n_in,
                              void* d_out, int out_size, void* d_ws, size_t ws_size,
                              hipStream_t stream) {
  const float* hidden   = (const float*)d_in[0];
  const float* enc      = (const float*)d_in[1];
  const float* Pq_in    = (const float*)d_in[2];
  const float* Pk_in    = (const float*)d_in[3];
  const float* Pv_in    = (const float*)d_in[4];
  const float* Pout_in  = (const float*)d_in[5];
  const float* Pq_out   = (const float*)d_in[6];
  const float* Pk_out   = (const float*)d_in[7];
  const float* Pv_out   = (const float*)d_in[8];
  const float* Pout_out = (const float*)d_in[9];
  const float* Wq       = (const float*)d_in[10];
  const float* Wk       = (const float*)d_in[11];
  const float* Wv       = (const float*)d_in[12];
  const float* Wout     = (const float*)d_in[13];
  const float* bout     = (const float*)d_in[14];
  const float* q_scale  = (const float*)d_in[15];
  const float* k_scale  = (const float*)d_in[16];
  const float* v_scale  = (const float*)d_in[17];
  const float* out_scale= (const float*)d_in[18];

  char* w = (char*)d_ws;
  unsigned short* attnO = (unsigned short*)w; w += 32768LL * 1280 * 2;
  unsigned short* WqT   = (unsigned short*)w; w += 1280LL * 1280 * 2;
  unsigned short* WkT   = (unsigned short*)w; w += 1280LL * 768 * 2;
  unsigned short* WvT   = (unsigned short*)w; w += 1280LL * 768 * 2;
  unsigned short* WoT   = (unsigned short*)w; w += 1280LL * 1280 * 2;
  unsigned short* Kbf   = (unsigned short*)w; w += 616LL * 1280 * 2;
  unsigned short* Vbf   = (unsigned short*)w; w += 616LL * 1280 * 2;
  float* cQq_in   = (float*)w; w += 16LL * 80 * 80 * 4;
  float* cQout_in = (float*)w; w += 16LL * 80 * 80 * 4;
  float* cQq_out  = (float*)w; w += 16LL * 80 * 80 * 4;
  float* cQk_out  = (float*)w; w += 16LL * 80 * 80 * 4;
  float* cQv_out  = (float*)w; w += 16LL * 80 * 80 * 4;
  float* cQout_out= (float*)w; w += 16LL * 80 * 80 * 4;
  float* cQk_in   = (float*)w; w += 16LL * 48 * 48 * 4;
  float* cQv_in   = (float*)w; w += 16LL * 48 * 48 * 4;

  // d_out doubles as scratch: [Xbf | Qbf] bf16; final GEMM overwrites with fp32.
  unsigned short* Xbf = (unsigned short*)d_out;
  unsigned short* Qbf = Xbf + 32768LL * 1280;

  CayleyPtrs cp;
  cp.P[0] = Pq_in;    cp.Q[0] = cQq_in;
  cp.P[1] = Pout_in;  cp.Q[1] = cQout_in;
  cp.P[2] = Pq_out;   cp.Q[2] = cQq_out;
  cp.P[3] = Pk_out;   cp.Q[3] = cQk_out;
  cp.P[4] = Pv_out;   cp.Q[4] = cQv_out;
  cp.P[5] = Pout_out; cp.Q[5] = cQout_out;
  cp.P[6] = Pk_in;    cp.Q[6] = cQk_in;
  cp.P[7] = Pv_in;    cp.Q[7] = cQv_in;
  cayley_all<<<128, 256, 0, stream>>>(cp);

  const float ATTN_SCALE = 0.07905694150420949f;  // 160^-0.5
  BuildArgs ba;
  ba.Qin[0] = cQq_in;   ba.W[0] = Wq;   ba.Qout[0] = cQq_out;   ba.scale[0] = q_scale;
  ba.WeffT[0] = WqT;    ba.extra[0] = ATTN_SCALE; ba.b[0] = 80; ba.Kin[0] = 1280;
  ba.Qin[1] = cQk_in;   ba.W[1] = Wk;   ba.Qout[1] = cQk_out;   ba.scale[1] = k_scale;
  ba.WeffT[1] = WkT;    ba.extra[1] = 1.0f;       ba.b[1] = 48; ba.Kin[1] = 768;
  ba.Qin[2] = cQv_in;   ba.W[2] = Wv;   ba.Qout[2] = cQv_out;   ba.scale[2] = v_scale;
  ba.WeffT[2] = WvT;    ba.extra[2] = 1.0f;       ba.b[2] = 48; ba.Kin[2] = 768;
  ba.Qin[3] = cQout_in; ba.W[3] = Wout; ba.Qout[3] = cQout_out; ba.scale[3] = out_scale;
  ba.WeffT[3] = WoT;    ba.extra[3] = 1.0f;       ba.b[3] = 80; ba.Kin[3] = 1280;
  build_all<<<dim3(16, 16, 4), 256, 0, stream>>>(ba);

  f32_to_bf16_kernel<<<2048, 256, 0, stream>>>(hidden, Xbf, 32768LL * 1280);

  // Q = Xbf @ WqT^T   (2560 blocks, XCD-swizzled)
  gemm_lds<false, false><<<2560, 256, 0, stream>>>(Xbf, WqT, Qbf, nullptr, 32768, 1280, 1280);
  // K,V projections (M=616, fp32 A)
  gemm_small_f32a<<<dim3(10, 5), 256, 0, stream>>>(enc, WkT, Kbf, 616, 1280, 768);
  gemm_small_f32a<<<dim3(10, 5), 256, 0, stream>>>(enc, WvT, Vbf, 616, 1280, 768);

  attn_kernel<<<dim3(64, 64), 256, 0, stream>>>(Qbf, Kbf, Vbf, attnO);

  // final: fp32 out + bias
  gemm_lds<true, true><<<2560, 256, 0, stream>>>(attnO, WoT, d_out, bout, 32768, 1280, 1280);
}

// Round 4
// 693.584 us; speedup vs baseline: 4.0254x; 1.1752x over previous
//
#include <hip/hip_runtime.h>

typedef __attribute__((ext_vector_type(4))) float f32x4;
typedef __attribute__((ext_vector_type(8))) short short8;
typedef __attribute__((ext_vector_type(8))) __bf16 bf16x8;
typedef __attribute__((ext_vector_type(4))) unsigned short us4;

__device__ __forceinline__ unsigned short f2bf(float f) {
  unsigned u = __builtin_bit_cast(unsigned, f);
  u = (u + 0x7FFFu + ((u >> 16) & 1u)) >> 16;
  return (unsigned short)u;
}

__device__ __forceinline__ f32x4 mfma16(short8 a, short8 b, f32x4 c) {
  return __builtin_amdgcn_mfma_f32_16x16x32_bf16(
      __builtin_bit_cast(bf16x8, a), __builtin_bit_cast(bf16x8, b), c, 0, 0, 0);
}

// async global->LDS, 16B per lane. LDS dest must be wave-uniform base; HW adds lane*16.
__device__ __forceinline__ void gload16(const unsigned short* g, unsigned short* l) {
  __builtin_amdgcn_global_load_lds((const __attribute__((address_space(1))) void*)g,
                                   (__attribute__((address_space(3))) void*)l, 16, 0, 0);
}

__device__ __forceinline__ float dot4(f32x4 x, f32x4 y) {
  return x[0] * y[0] + x[1] * y[1] + x[2] * y[2] + x[3] * y[3];
}

// ---------------------------------------------------------------------------
// Fused Cayley for all 8 parameter tensors in ONE launch (128 blocks).
// Unpivoted Gauss-Jordan, deferred row scaling.
// ---------------------------------------------------------------------------
struct CayleyPtrs {
  const float* P[8];
  float* Q[8];
};

__launch_bounds__(256)
__global__ void cayley_all(CayleyPtrs ptrs) {
  __shared__ float M[80 * 80];
  __shared__ float R[80 * 80];
  __shared__ float fcol[80];
  int t = blockIdx.x >> 4, g = blockIdx.x & 15;
  int n = (t < 6) ? 80 : 48;
  int tid = threadIdx.x;
  const float* Pg = ptrs.P[t] + (size_t)g * n * n;
  float* Qg = ptrs.Q[t] + (size_t)g * n * n;

  for (int idx = tid; idx < n * n; idx += 256) {
    int i = idx / n, j = idx - i * n;
    float a = Pg[i * n + j] - Pg[j * n + i];
    float id = (i == j) ? 1.0f : 0.0f;
    M[idx] = id - a;
    R[idx] = id + a;
  }
  __syncthreads();

  int nch = n >> 2;
  int tot = n * nch;
  for (int k = 0; k < n; ++k) {
    if (tid < n) {
      float inv = 1.0f / M[k * n + k];
      fcol[tid] = (tid == k) ? 0.0f : M[tid * n + k] * inv;
    }
    __syncthreads();
    for (int idx = tid; idx < tot; idx += 256) {
      int i = idx / nch, c = idx - i * nch;
      float f = fcol[i];
      ((f32x4*)&R[i * n])[c] = ((f32x4*)&R[i * n])[c] - f * ((const f32x4*)&R[k * n])[c];
    }
    int c0 = k >> 2, mw = nch - c0, totM = n * mw;
    for (int idx = tid; idx < totM; idx += 256) {
      int i = idx / mw, c = c0 + idx - i * mw;
      float f = fcol[i];
      ((f32x4*)&M[i * n])[c] = ((f32x4*)&M[i * n])[c] - f * ((const f32x4*)&M[k * n])[c];
    }
    __syncthreads();
  }
  for (int idx = tid; idx < n * n; idx += 256) {
    int i = idx / n;
    Qg[idx] = R[idx] / M[i * n + i];
  }
}

// ---------------------------------------------------------------------------
// Fused effective weights, all 4 tensors in one launch: grid (16,16,4).
// v2: 4x4 register blocking (2 B/MAC LDS traffic), stride-84 LDS rows
// (16B-aligned, conflict-spread), 3 buffers (QoT reuses Qs) -> 2 blocks/CU.
// ---------------------------------------------------------------------------
struct BuildArgs {
  const float* Qin[4];
  const float* W[4];
  const float* Qout[4];
  const float* scale[4];
  unsigned short* WeffT[4];
  float extra[4];
  int b[4];
  int Kin[4];
};

#define BS 84  // LDS row stride in floats: 84*4 B = 16B-aligned, 84 % 32 = 20

__launch_bounds__(256)
__global__ void build_all(BuildArgs A) {
  __shared__ float Qs[80 * BS];  // Qin rows; later QoT (QoT[n][m] = Qout[m][n])
  __shared__ float Ws[80 * BS];  // W rows [m][j]
  __shared__ float T1[80 * BS];  // T1[i][m]
  int z = blockIdx.z;
  int gi = blockIdx.x, go = blockIdx.y, tid = threadIdx.x;
  int b = A.b[z], Kin = A.Kin[z];
  float extra = A.extra[z];
  const float* Qin = A.Qin[z];
  const float* W = A.W[z];
  const float* Qout = A.Qout[z];
  const float* scale = A.scale[z];
  unsigned short* WeffT = A.WeffT[z];

  // stage Qin (b x b) and W rows (80 x b)
  for (int idx = tid; idx < b * b; idx += 256) {
    int i = idx / b, j = idx - i * b;
    Qs[i * BS + j] = Qin[(size_t)gi * b * b + idx];
  }
  for (int idx = tid; idx < 80 * b; idx += 256) {
    int m = idx / b, j = idx - m * b;
    Ws[m * BS + j] = W[(size_t)(go * 80 + m) * Kin + gi * b + j];
  }
  __syncthreads();

  int itiles = b >> 2;           // 20 (b=80) or 12 (b=48)
  int jch = b >> 2;              // j-chunks of 4
  int NT = itiles * 20;
  // product 1: T1[i][m] = sum_j Qs[i][j] * Ws[m][j]
  for (int t = tid; t < NT; t += 256) {
    int ti = t / 20, tm = t - ti * 20;
    float acc[4][4] = {};
    for (int jc = 0; jc < jch; ++jc) {
      f32x4 qa[4], wb[4];
#pragma unroll
      for (int p = 0; p < 4; ++p) qa[p] = *(const f32x4*)&Qs[(4 * ti + p) * BS + jc * 4];
#pragma unroll
      for (int p = 0; p < 4; ++p) wb[p] = *(const f32x4*)&Ws[(4 * tm + p) * BS + jc * 4];
#pragma unroll
      for (int p = 0; p < 4; ++p)
#pragma unroll
        for (int q = 0; q < 4; ++q) acc[p][q] += dot4(qa[p], wb[q]);
    }
#pragma unroll
    for (int p = 0; p < 4; ++p)
#pragma unroll
      for (int q = 0; q < 4; ++q) T1[(4 * ti + p) * BS + 4 * tm + q] = acc[p][q];
  }
  __syncthreads();
  // stage QoT into Qs buffer: QoT[n][m] = Qout[go][m][n]
  for (int idx = tid; idx < 6400; idx += 256) {
    int m = idx / 80, n = idx - m * 80;
    Qs[n * BS + m] = Qout[(size_t)go * 6400 + idx];
  }
  __syncthreads();
  // product 2: Out[i][n] = sum_m T1[i][m] * QoT[n][m]
  for (int t = tid; t < NT; t += 256) {
    int ti = t / 20, tn = t - ti * 20;
    float acc[4][4] = {};
    for (int mc = 0; mc < 20; ++mc) {
      f32x4 ta[4], qb[4];
#pragma unroll
      for (int p = 0; p < 4; ++p) ta[p] = *(const f32x4*)&T1[(4 * ti + p) * BS + mc * 4];
#pragma unroll
      for (int p = 0; p < 4; ++p) qb[p] = *(const f32x4*)&Qs[(4 * tn + p) * BS + mc * 4];
#pragma unroll
      for (int p = 0; p < 4; ++p)
#pragma unroll
        for (int q = 0; q < 4; ++q) acc[p][q] += dot4(ta[p], qb[q]);
    }
#pragma unroll
    for (int q = 0; q < 4; ++q) {
      int col = go * 80 + 4 * tn + q;
      float sc = scale[col] * extra;
#pragma unroll
      for (int p = 0; p < 4; ++p)
        WeffT[(size_t)col * Kin + gi * b + 4 * ti + p] = f2bf(acc[p][q] * sc);
    }
  }
}

// ---------------------------------------------------------------------------
// fp32 -> bf16 bulk convert
// ---------------------------------------------------------------------------
__launch_bounds__(256)
__global__ void f32_to_bf16_kernel(const float* __restrict__ in, unsigned short* __restrict__ out,
                                   long long n) {
  long long i = ((long long)blockIdx.x * 256 + threadIdx.x) * 4;
  long long stride = (long long)gridDim.x * 256 * 4;
  for (; i < n; i += stride) {
    f32x4 v = *(const f32x4*)(in + i);
    us4 o;
    o[0] = f2bf(v[0]); o[1] = f2bf(v[1]); o[2] = f2bf(v[2]); o[3] = f2bf(v[3]);
    *(us4*)(out + i) = o;
  }
}

// ---------------------------------------------------------------------------
// m97-style bf16 MFMA GEMM: C[M,N] = A[M,K] @ Bt[N,K]^T.
// 128x128 tile, BK=32, 4 waves, linear LDS, global_load_lds width=16,
// XCD-aware bijective block swizzle (nwg % 8 == 0).
// ---------------------------------------------------------------------------
template <bool CF32, bool BIAS>
__launch_bounds__(256)
__global__ void gemm_lds(const unsigned short* __restrict__ A,
                         const unsigned short* __restrict__ Bt,
                         void* __restrict__ Cp, const float* __restrict__ bias,
                         int M, int N, int K) {
  __shared__ alignas(128) unsigned short As[128 * 32];
  __shared__ alignas(128) unsigned short Bs[128 * 32];
  int nwg = gridDim.x;
  int per = nwg >> 3;
  int bid = blockIdx.x;
  int nid = (bid & 7) * per + (bid >> 3);
  int nbn = N >> 7;
  int bm = nid / nbn, bn = nid - bm * nbn;

  int tid = threadIdx.x;
  int l = tid & 63, w = tid >> 6, lo = l & 15, hi = l >> 4;
  int wm = w >> 1, wn = w & 1;
  int row0 = bm * 128, col0 = bn * 128;

  int srow = (l >> 2);
  int schk = (l & 3) * 8;
  const unsigned short* a0 = A + (size_t)(row0 + w * 32 + srow) * K + schk;
  const unsigned short* a1 = a0 + (size_t)16 * K;
  const unsigned short* b0 = Bt + (size_t)(col0 + w * 32 + srow) * K + schk;
  const unsigned short* b1 = b0 + (size_t)16 * K;
  unsigned short* lAs0 = &As[(w * 32) * 32];
  unsigned short* lAs1 = &As[(w * 32 + 16) * 32];
  unsigned short* lBs0 = &Bs[(w * 32) * 32];
  unsigned short* lBs1 = &Bs[(w * 32 + 16) * 32];

  f32x4 z = {0.0f, 0.0f, 0.0f, 0.0f};
  f32x4 acc[4][4];
#pragma unroll
  for (int m = 0; m < 4; ++m)
#pragma unroll
    for (int n = 0; n < 4; ++n) acc[m][n] = z;

  for (int k0 = 0; k0 < K; k0 += 32) {
    gload16(a0 + k0, lAs0);
    gload16(a1 + k0, lAs1);
    gload16(b0 + k0, lBs0);
    gload16(b1 + k0, lBs1);
    __syncthreads();
    short8 af[4], bf[4];
#pragma unroll
    for (int m = 0; m < 4; ++m) af[m] = *(const short8*)&As[(wm * 64 + m * 16 + lo) * 32 + hi * 8];
#pragma unroll
    for (int n = 0; n < 4; ++n) bf[n] = *(const short8*)&Bs[(wn * 64 + n * 16 + lo) * 32 + hi * 8];
#pragma unroll
    for (int m = 0; m < 4; ++m)
#pragma unroll
      for (int n = 0; n < 4; ++n) acc[m][n] = mfma16(af[m], bf[n], acc[m][n]);
    __syncthreads();
  }

#pragma unroll
  for (int m = 0; m < 4; ++m)
#pragma unroll
    for (int n = 0; n < 4; ++n) {
      int col = col0 + wn * 64 + n * 16 + lo;
#pragma unroll
      for (int j = 0; j < 4; ++j) {
        int row = row0 + wm * 64 + m * 16 + hi * 4 + j;
        float v = acc[m][n][j];
        if (BIAS) v += bias[col];
        if (CF32) ((float*)Cp)[(size_t)row * N + col] = v;
        else ((unsigned short*)Cp)[(size_t)row * N + col] = f2bf(v);
      }
    }
}

// ---------------------------------------------------------------------------
// reg-staged GEMM for small fp32-A cases (M guarded): K/V projections.
// ---------------------------------------------------------------------------
__launch_bounds__(256)
__global__ void gemm_small_f32a(const float* __restrict__ Ap, const unsigned short* __restrict__ Bt,
                                unsigned short* __restrict__ Cp, int M, int N, int K) {
  __shared__ unsigned short As[128][40];
  __shared__ unsigned short Bs[128][40];
  int bn = blockIdx.x, bm = blockIdx.y;
  int tid = threadIdx.x;
  int l = tid & 63, wid = tid >> 6, lo = l & 15, hi = l >> 4;
  int wm = wid >> 1, wn = wid & 1;
  f32x4 z = {0.0f, 0.0f, 0.0f, 0.0f};
  f32x4 acc[4][4];
#pragma unroll
  for (int m = 0; m < 4; ++m)
#pragma unroll
    for (int n = 0; n < 4; ++n) acc[m][n] = z;
  int row0 = bm * 128;
  int ar = tid >> 2, acg = tid & 3;
  int bnr = tid >> 1, bhf = tid & 1;

  for (int k0 = 0; k0 < K; k0 += 32) {
    __syncthreads();
#pragma unroll
    for (int rr = 0; rr < 2; ++rr) {
      int row = ar + rr * 64;
      int grow = row0 + row;
      short8 v = {0, 0, 0, 0, 0, 0, 0, 0};
      if (grow < M) {
        const float* ap = Ap + (size_t)grow * K + k0 + acg * 8;
        f32x4 v0 = *(const f32x4*)ap;
        f32x4 v1 = *(const f32x4*)(ap + 4);
        v[0] = (short)f2bf(v0[0]); v[1] = (short)f2bf(v0[1]);
        v[2] = (short)f2bf(v0[2]); v[3] = (short)f2bf(v0[3]);
        v[4] = (short)f2bf(v1[0]); v[5] = (short)f2bf(v1[1]);
        v[6] = (short)f2bf(v1[2]); v[7] = (short)f2bf(v1[3]);
      }
      *(short8*)&As[row][acg * 8] = v;
    }
    {
      const unsigned short* bp = Bt + (size_t)(bn * 128 + bnr) * K + k0 + bhf * 16;
      *(short8*)&Bs[bnr][bhf * 16] = *(const short8*)bp;
      *(short8*)&Bs[bnr][bhf * 16 + 8] = *(const short8*)(bp + 8);
    }
    __syncthreads();
    short8 af[4], bf[4];
#pragma unroll
    for (int m = 0; m < 4; ++m) af[m] = *(const short8*)&As[wm * 64 + m * 16 + lo][hi * 8];
#pragma unroll
    for (int n = 0; n < 4; ++n) bf[n] = *(const short8*)&Bs[wn * 64 + n * 16 + lo][hi * 8];
#pragma unroll
    for (int m = 0; m < 4; ++m)
#pragma unroll
      for (int n = 0; n < 4; ++n) acc[m][n] = mfma16(af[m], bf[n], acc[m][n]);
  }

#pragma unroll
  for (int m = 0; m < 4; ++m)
#pragma unroll
    for (int n = 0; n < 4; ++n) {
      int col = bn * 128 + wn * 64 + n * 16 + lo;
#pragma unroll
      for (int j = 0; j < 4; ++j) {
        int row = row0 + wm * 64 + m * 16 + hi * 4 + j;
        if (row < M) Cp[(size_t)row * N + col] = f2bf(acc[m][n][j]);
      }
    }
}

// ---------------------------------------------------------------------------
// Attention: Sk=77 single tile. Q/K read straight from global (L2-fit);
// only V^T and P go through LDS.
// ---------------------------------------------------------------------------
#define QB 64
__launch_bounds__(256)
__global__ void attn_kernel(const unsigned short* __restrict__ Q,
                            const unsigned short* __restrict__ Kp,
                            const unsigned short* __restrict__ Vp,
                            unsigned short* __restrict__ O) {
  __shared__ alignas(16) unsigned short Vt[160][104];
  __shared__ alignas(16) unsigned short Ps[QB][104];
  int tile = blockIdx.x, bh = blockIdx.y;
  int b = bh >> 3, h = bh & 7;
  int tid = threadIdx.x;

  const unsigned short* Vb = Vp + (size_t)(b * 77) * 1280 + h * 160;
  for (int cid = tid; cid < 77 * 20; cid += 256) {
    int t = cid / 20, c = cid - t * 20;
    short8 v = *(const short8*)&Vb[(size_t)t * 1280 + c * 8];
#pragma unroll
    for (int j = 0; j < 8; ++j) Vt[c * 8 + j][t] = (unsigned short)v[j];
  }
  for (int cid = tid; cid < 160 * 27; cid += 256) {
    int d = cid / 27, t = 77 + (cid - d * 27);
    Vt[d][t] = 0;
  }
  for (int cid = tid; cid < QB * 16; cid += 256) {
    int r = cid / 16, c = 80 + (cid & 15);
    Ps[r][c] = 0;
  }

  int l = tid & 63, wid = tid >> 6, lo = l & 15, hi = l >> 4;

  const unsigned short* qrow =
      Q + (size_t)(b * 4096 + tile * QB + wid * 16 + lo) * 1280 + h * 160;
  short8 a[5];
#pragma unroll
  for (int kt = 0; kt < 5; ++kt) a[kt] = *(const short8*)&qrow[kt * 32 + hi * 8];

  const unsigned short* Kb = Kp + (size_t)(b * 77) * 1280 + h * 160;
  f32x4 z = {0.0f, 0.0f, 0.0f, 0.0f};
  f32x4 sc[5];
#pragma unroll
  for (int n = 0; n < 5; ++n) sc[n] = z;
#pragma unroll
  for (int n = 0; n < 5; ++n) {
    const unsigned short* krow = Kb + (size_t)(n * 16 + lo) * 1280;
#pragma unroll
    for (int kt = 0; kt < 5; ++kt) {
      short8 bb = *(const short8*)&krow[kt * 32 + hi * 8];
      sc[n] = mfma16(a[kt], bb, sc[n]);
    }
  }
  if (lo >= 13) { sc[4][0] = -1e30f; sc[4][1] = -1e30f; sc[4][2] = -1e30f; sc[4][3] = -1e30f; }

  float pinv[4];
#pragma unroll
  for (int j = 0; j < 4; ++j) {
    float mx = sc[0][j];
#pragma unroll
    for (int n = 1; n < 5; ++n) mx = fmaxf(mx, sc[n][j]);
#pragma unroll
    for (int msk = 1; msk < 16; msk <<= 1) mx = fmaxf(mx, __shfl_xor(mx, msk, 64));
    float s = 0.0f;
#pragma unroll
    for (int n = 0; n < 5; ++n) {
      float p = __expf(sc[n][j] - mx);
      sc[n][j] = p;
      s += p;
    }
#pragma unroll
    for (int msk = 1; msk < 16; msk <<= 1) s += __shfl_xor(s, msk, 64);
    pinv[j] = 1.0f / s;
  }
#pragma unroll
  for (int n = 0; n < 5; ++n)
#pragma unroll
    for (int j = 0; j < 4; ++j)
      Ps[wid * 16 + hi * 4 + j][n * 16 + lo] = f2bf(sc[n][j] * pinv[j]);
  __syncthreads();

  f32x4 o[10];
#pragma unroll
  for (int n = 0; n < 10; ++n) o[n] = z;
#pragma unroll
  for (int kt = 0; kt < 3; ++kt) {
    short8 pa = *(const short8*)&Ps[wid * 16 + lo][kt * 32 + hi * 8];
#pragma unroll
    for (int n = 0; n < 10; ++n) {
      short8 vb = *(const short8*)&Vt[n * 16 + lo][kt * 32 + hi * 8];
      o[n] = mfma16(pa, vb, o[n]);
    }
  }
  unsigned short* Ob = O + (size_t)(b * 4096 + tile * QB + wid * 16 + hi * 4) * 1280 + h * 160;
#pragma unroll
  for (int n = 0; n < 10; ++n)
#pragma unroll
    for (int j = 0; j < 4; ++j)
      Ob[(size_t)j * 1280 + n * 16 + lo] = f2bf(o[n][j]);
}

// ---------------------------------------------------------------------------
extern "C" void kernel_launch(void* const* d_in, const int* in_sizes, int n_in,
                              void* d_out, int out_size, void* d_ws, size_t ws_size,
                              hipStream_t stream) {
  const float* hidden   = (const float*)d_in[0];
  const float* enc      = (const float*)d_in[1];
  const float* Pq_in    = (const float*)d_in[2];
  const float* Pk_in    = (const float*)d_in[3];
  const float* Pv_in    = (const float*)d_in[4];
  const float* Pout_in  = (const float*)d_in[5];
  const float* Pq_out   = (const float*)d_in[6];
  const float* Pk_out   = (const float*)d_in[7];
  const float* Pv_out   = (const float*)d_in[8];
  const float* Pout_out = (const float*)d_in[9];
  const float* Wq       = (const float*)d_in[10];
  const float* Wk       = (const float*)d_in[11];
  const float* Wv       = (const float*)d_in[12];
  const float* Wout     = (const float*)d_in[13];
  const float* bout     = (const float*)d_in[14];
  const float* q_scale  = (const float*)d_in[15];
  const float* k_scale  = (const float*)d_in[16];
  const float* v_scale  = (const float*)d_in[17];
  const float* out_scale= (const float*)d_in[18];

  char* w = (char*)d_ws;
  unsigned short* attnO = (unsigned short*)w; w += 32768LL * 1280 * 2;
  unsigned short* WqT   = (unsigned short*)w; w += 1280LL * 1280 * 2;
  unsigned short* WkT   = (unsigned short*)w; w += 1280LL * 768 * 2;
  unsigned short* WvT   = (unsigned short*)w; w += 1280LL * 768 * 2;
  unsigned short* WoT   = (unsigned short*)w; w += 1280LL * 1280 * 2;
  unsigned short* Kbf   = (unsigned short*)w; w += 616LL * 1280 * 2;
  unsigned short* Vbf   = (unsigned short*)w; w += 616LL * 1280 * 2;
  float* cQq_in   = (float*)w; w += 16LL * 80 * 80 * 4;
  float* cQout_in = (float*)w; w += 16LL * 80 * 80 * 4;
  float* cQq_out  = (float*)w; w += 16LL * 80 * 80 * 4;
  float* cQk_out  = (float*)w; w += 16LL * 80 * 80 * 4;
  float* cQv_out  = (float*)w; w += 16LL * 80 * 80 * 4;
  float* cQout_out= (float*)w; w += 16LL * 80 * 80 * 4;
  float* cQk_in   = (float*)w; w += 16LL * 48 * 48 * 4;
  float* cQv_in   = (float*)w; w += 16LL * 48 * 48 * 4;

  unsigned short* Xbf = (unsigned short*)d_out;
  unsigned short* Qbf = Xbf + 32768LL * 1280;

  CayleyPtrs cp;
  cp.P[0] = Pq_in;    cp.Q[0] = cQq_in;
  cp.P[1] = Pout_in;  cp.Q[1] = cQout_in;
  cp.P[2] = Pq_out;   cp.Q[2] = cQq_out;
  cp.P[3] = Pk_out;   cp.Q[3] = cQk_out;
  cp.P[4] = Pv_out;   cp.Q[4] = cQv_out;
  cp.P[5] = Pout_out; cp.Q[5] = cQout_out;
  cp.P[6] = Pk_in;    cp.Q[6] = cQk_in;
  cp.P[7] = Pv_in;    cp.Q[7] = cQv_in;
  cayley_all<<<128, 256, 0, stream>>>(cp);

  const float ATTN_SCALE = 0.07905694150420949f;  // 160^-0.5
  BuildArgs ba;
  ba.Qin[0] = cQq_in;   ba.W[0] = Wq;   ba.Qout[0] = cQq_out;   ba.scale[0] = q_scale;
  ba.WeffT[0] = WqT;    ba.extra[0] = ATTN_SCALE; ba.b[0] = 80; ba.Kin[0] = 1280;
  ba.Qin[1] = cQk_in;   ba.W[1] = Wk;   ba.Qout[1] = cQk_out;   ba.scale[1] = k_scale;
  ba.WeffT[1] = WkT;    ba.extra[1] = 1.0f;       ba.b[1] = 48; ba.Kin[1] = 768;
  ba.Qin[2] = cQv_in;   ba.W[2] = Wv;   ba.Qout[2] = cQv_out;   ba.scale[2] = v_scale;
  ba.WeffT[2] = WvT;    ba.extra[2] = 1.0f;       ba.b[2] = 48; ba.Kin[2] = 768;
  ba.Qin[3] = cQout_in; ba.W[3] = Wout; ba.Qout[3] = cQout_out; ba.scale[3] = out_scale;
  ba.WeffT[3] = WoT;    ba.extra[3] = 1.0f;       ba.b[3] = 80; ba.Kin[3] = 1280;
  build_all<<<dim3(16, 16, 4), 256, 0, stream>>>(ba);

  f32_to_bf16_kernel<<<2048, 256, 0, stream>>>(hidden, Xbf, 32768LL * 1280);

  gemm_lds<false, false><<<2560, 256, 0, stream>>>(Xbf, WqT, Qbf, nullptr, 32768, 1280, 1280);
  gemm_small_f32a<<<dim3(10, 5), 256, 0, stream>>>(enc, WkT, Kbf, 616, 1280, 768);
  gemm_small_f32a<<<dim3(10, 5), 256, 0, stream>>>(enc, WvT, Vbf, 616, 1280, 768);

  attn_kernel<<<dim3(64, 64), 256, 0, stream>>>(Qbf, Kbf, Vbf, attnO);

  gemm_lds<true, true><<<2560, 256, 0, stream>>>(attnO, WoT, d_out, bout, 32768, 1280, 1280);
}

// Round 5
// 686.953 us; speedup vs baseline: 4.0643x; 1.0097x over previous
//
#include <hip/hip_runtime.h>

typedef __attribute__((ext_vector_type(4))) float f32x4;
typedef __attribute__((ext_vector_type(8))) short short8;
typedef __attribute__((ext_vector_type(8))) __bf16 bf16x8;
typedef __attribute__((ext_vector_type(4))) unsigned short us4;

__device__ __forceinline__ unsigned short f2bf(float f) {
  unsigned u = __builtin_bit_cast(unsigned, f);
  u = (u + 0x7FFFu + ((u >> 16) & 1u)) >> 16;
  return (unsigned short)u;
}

__device__ __forceinline__ f32x4 mfma16(short8 a, short8 b, f32x4 c) {
  return __builtin_amdgcn_mfma_f32_16x16x32_bf16(
      __builtin_bit_cast(bf16x8, a), __builtin_bit_cast(bf16x8, b), c, 0, 0, 0);
}

// async global->LDS, 16B per lane. LDS dest must be wave-uniform base; HW adds lane*16.
__device__ __forceinline__ void gload16(const unsigned short* g, unsigned short* l) {
  __builtin_amdgcn_global_load_lds((const __attribute__((address_space(1))) void*)g,
                                   (__attribute__((address_space(3))) void*)l, 16, 0, 0);
}

__device__ __forceinline__ float dot4(f32x4 x, f32x4 y) {
  return x[0] * y[0] + x[1] * y[1] + x[2] * y[2] + x[3] * y[3];
}

// ---------------------------------------------------------------------------
// Fused Cayley for all 8 parameter tensors in ONE launch (128 blocks).
// ---------------------------------------------------------------------------
struct CayleyPtrs {
  const float* P[8];
  float* Q[8];
};

__launch_bounds__(256)
__global__ void cayley_all(CayleyPtrs ptrs) {
  __shared__ float M[80 * 80];
  __shared__ float R[80 * 80];
  __shared__ float fcol[80];
  int t = blockIdx.x >> 4, g = blockIdx.x & 15;
  int n = (t < 6) ? 80 : 48;
  int tid = threadIdx.x;
  const float* Pg = ptrs.P[t] + (size_t)g * n * n;
  float* Qg = ptrs.Q[t] + (size_t)g * n * n;

  for (int idx = tid; idx < n * n; idx += 256) {
    int i = idx / n, j = idx - i * n;
    float a = Pg[i * n + j] - Pg[j * n + i];
    float id = (i == j) ? 1.0f : 0.0f;
    M[idx] = id - a;
    R[idx] = id + a;
  }
  __syncthreads();

  int nch = n >> 2;
  int tot = n * nch;
  for (int k = 0; k < n; ++k) {
    if (tid < n) {
      float inv = 1.0f / M[k * n + k];
      fcol[tid] = (tid == k) ? 0.0f : M[tid * n + k] * inv;
    }
    __syncthreads();
    for (int idx = tid; idx < tot; idx += 256) {
      int i = idx / nch, c = idx - i * nch;
      float f = fcol[i];
      ((f32x4*)&R[i * n])[c] = ((f32x4*)&R[i * n])[c] - f * ((const f32x4*)&R[k * n])[c];
    }
    int c0 = k >> 2, mw = nch - c0, totM = n * mw;
    for (int idx = tid; idx < totM; idx += 256) {
      int i = idx / mw, c = c0 + idx - i * mw;
      float f = fcol[i];
      ((f32x4*)&M[i * n])[c] = ((f32x4*)&M[i * n])[c] - f * ((const f32x4*)&M[k * n])[c];
    }
    __syncthreads();
  }
  for (int idx = tid; idx < n * n; idx += 256) {
    int i = idx / n;
    Qg[idx] = R[idx] / M[i * n + i];
  }
}

// ---------------------------------------------------------------------------
// Fused effective weights, all 4 tensors: grid (16,16,4). 4x4 reg blocking.
// ---------------------------------------------------------------------------
struct BuildArgs {
  const float* Qin[4];
  const float* W[4];
  const float* Qout[4];
  const float* scale[4];
  unsigned short* WeffT[4];
  float extra[4];
  int b[4];
  int Kin[4];
};

#define BS 84  // LDS row stride in floats

__launch_bounds__(256)
__global__ void build_all(BuildArgs A) {
  __shared__ float Qs[80 * BS];
  __shared__ float Ws[80 * BS];
  __shared__ float T1[80 * BS];
  int z = blockIdx.z;
  int gi = blockIdx.x, go = blockIdx.y, tid = threadIdx.x;
  int b = A.b[z], Kin = A.Kin[z];
  float extra = A.extra[z];
  const float* Qin = A.Qin[z];
  const float* W = A.W[z];
  const float* Qout = A.Qout[z];
  const float* scale = A.scale[z];
  unsigned short* WeffT = A.WeffT[z];

  for (int idx = tid; idx < b * b; idx += 256) {
    int i = idx / b, j = idx - i * b;
    Qs[i * BS + j] = Qin[(size_t)gi * b * b + idx];
  }
  for (int idx = tid; idx < 80 * b; idx += 256) {
    int m = idx / b, j = idx - m * b;
    Ws[m * BS + j] = W[(size_t)(go * 80 + m) * Kin + gi * b + j];
  }
  __syncthreads();

  int itiles = b >> 2;
  int jch = b >> 2;
  int NT = itiles * 20;
  for (int t = tid; t < NT; t += 256) {
    int ti = t / 20, tm = t - ti * 20;
    float acc[4][4] = {};
    for (int jc = 0; jc < jch; ++jc) {
      f32x4 qa[4], wb[4];
#pragma unroll
      for (int p = 0; p < 4; ++p) qa[p] = *(const f32x4*)&Qs[(4 * ti + p) * BS + jc * 4];
#pragma unroll
      for (int p = 0; p < 4; ++p) wb[p] = *(const f32x4*)&Ws[(4 * tm + p) * BS + jc * 4];
#pragma unroll
      for (int p = 0; p < 4; ++p)
#pragma unroll
        for (int q = 0; q < 4; ++q) acc[p][q] += dot4(qa[p], wb[q]);
    }
#pragma unroll
    for (int p = 0; p < 4; ++p)
#pragma unroll
      for (int q = 0; q < 4; ++q) T1[(4 * ti + p) * BS + 4 * tm + q] = acc[p][q];
  }
  __syncthreads();
  for (int idx = tid; idx < 6400; idx += 256) {
    int m = idx / 80, n = idx - m * 80;
    Qs[n * BS + m] = Qout[(size_t)go * 6400 + idx];
  }
  __syncthreads();
  for (int t = tid; t < NT; t += 256) {
    int ti = t / 20, tn = t - ti * 20;
    float acc[4][4] = {};
    for (int mc = 0; mc < 20; ++mc) {
      f32x4 ta[4], qb[4];
#pragma unroll
      for (int p = 0; p < 4; ++p) ta[p] = *(const f32x4*)&T1[(4 * ti + p) * BS + mc * 4];
#pragma unroll
      for (int p = 0; p < 4; ++p) qb[p] = *(const f32x4*)&Qs[(4 * tn + p) * BS + mc * 4];
#pragma unroll
      for (int p = 0; p < 4; ++p)
#pragma unroll
        for (int q = 0; q < 4; ++q) acc[p][q] += dot4(ta[p], qb[q]);
    }
#pragma unroll
    for (int q = 0; q < 4; ++q) {
      int col = go * 80 + 4 * tn + q;
      float sc = scale[col] * extra;
#pragma unroll
      for (int p = 0; p < 4; ++p)
        WeffT[(size_t)col * Kin + gi * b + 4 * ti + p] = f2bf(acc[p][q] * sc);
    }
  }
}

// ---------------------------------------------------------------------------
// fp32 -> bf16 bulk convert
// ---------------------------------------------------------------------------
__launch_bounds__(256)
__global__ void f32_to_bf16_kernel(const float* __restrict__ in, unsigned short* __restrict__ out,
                                   long long n) {
  long long i = ((long long)blockIdx.x * 256 + threadIdx.x) * 4;
  long long stride = (long long)gridDim.x * 256 * 4;
  for (; i < n; i += stride) {
    f32x4 v = *(const f32x4*)(in + i);
    us4 o;
    o[0] = f2bf(v[0]); o[1] = f2bf(v[1]); o[2] = f2bf(v[2]); o[3] = f2bf(v[3]);
    *(us4*)(out + i) = o;
  }
}

// ---------------------------------------------------------------------------
// 8-phase 256x256 bf16 MFMA GEMM (T3+T4+T2+T5): C[M,N] = A[M,K] @ Bt[N,K]^T.
// BK=64, 512 threads (8 waves, 2Mx4N), double-buffered 128KB linear LDS via
// global_load_lds w=16, XOR slot-swizzle (inverse-swz source + swz read),
// 4 phases/K-tile {12 ds_read -> s_barrier -> setprio1 -> 16 MFMA -> setprio0
// -> s_barrier}, prefetch issued at phase 0, vmcnt drained only at the
// per-tile __syncthreads (loads in flight across intra-tile barriers).
// Requires M%256==0, N%256==0, K%64==0, grid = (M/256)*(N/256) % 8 == 0.
// ---------------------------------------------------------------------------
template <bool CF32, bool BIAS>
__launch_bounds__(512, 2)
__global__ void gemm256(const unsigned short* __restrict__ A,
                        const unsigned short* __restrict__ Bt,
                        void* __restrict__ Cp, const float* __restrict__ bias,
                        int M, int N, int K) {
  __shared__ alignas(128) unsigned short AsL[2][256 * 64];
  __shared__ alignas(128) unsigned short BsL[2][256 * 64];
  int per = gridDim.x >> 3;
  int bid = blockIdx.x;
  int nid = (bid & 7) * per + (bid >> 3);
  int nbn = N >> 8;
  int bm = nid / nbn, bn = nid - bm * nbn;
  int row0 = bm << 8, col0 = bn << 8;

  int tid = threadIdx.x;
  int w = tid >> 6, l = tid & 63, lo = l & 15, hi = l >> 4;
  int wm = w >> 2, wn = w & 3;
  int rsw = lo & 7;

  // staging geometry: wave w covers rows [w*32, w*32+32), 4 issues of 8 rows.
  // LDS slot s of row r holds global chunk s^(r&7)  (involution swizzle).
  int sr8 = l >> 3;
  int chunk = (l & 7) ^ sr8;
  const unsigned short* Ag = A + (size_t)(row0 + w * 32 + sr8) * K + chunk * 8;
  const unsigned short* Bg = Bt + (size_t)(col0 + w * 32 + sr8) * K + chunk * 8;

  int NT = K >> 6;

  f32x4 z = {0.0f, 0.0f, 0.0f, 0.0f};
  f32x4 acc[8][4];
#pragma unroll
  for (int m = 0; m < 8; ++m)
#pragma unroll
    for (int n = 0; n < 4; ++n) acc[m][n] = z;

  auto stage = [&](int t, int X) {
    const unsigned short* ag = Ag + t * 64;
    const unsigned short* bg = Bg + t * 64;
    unsigned short* la = &AsL[X][w * 2048];
    unsigned short* lb = &BsL[X][w * 2048];
#pragma unroll
    for (int i = 0; i < 4; ++i) {
      gload16(ag + (size_t)(i * 8) * K, la + i * 512);
      gload16(bg + (size_t)(i * 8) * K, lb + i * 512);
    }
  };

  stage(0, 0);
  __syncthreads();  // drains vmcnt(0): tile 0 landed

  for (int t = 0; t < NT; ++t) {
    int X = t & 1;
    const unsigned short* cA = &AsL[X][0];
    const unsigned short* cB = &BsL[X][0];
#pragma unroll
    for (int p = 0; p < 4; ++p) {
      const int mq = p >> 1, nq = p & 1;
      short8 af[4][2], bf[2][2];
#pragma unroll
      for (int mi = 0; mi < 4; ++mi) {
        int row = wm * 128 + (mq * 4 + mi) * 16 + lo;
#pragma unroll
        for (int kk = 0; kk < 2; ++kk)
          af[mi][kk] = *(const short8*)&cA[row * 64 + ((kk * 4 + hi) ^ rsw) * 8];
      }
#pragma unroll
      for (int ni = 0; ni < 2; ++ni) {
        int col = wn * 64 + (nq * 2 + ni) * 16 + lo;
#pragma unroll
        for (int kk = 0; kk < 2; ++kk)
          bf[ni][kk] = *(const short8*)&cB[col * 64 + ((kk * 4 + hi) ^ rsw) * 8];
      }
      if (p == 0 && t + 1 < NT) stage(t + 1, X ^ 1);  // issue-early prefetch
      __builtin_amdgcn_s_barrier();
      __builtin_amdgcn_s_setprio(1);
#pragma unroll
      for (int mi = 0; mi < 4; ++mi)
#pragma unroll
        for (int ni = 0; ni < 2; ++ni) {
          int m = mq * 4 + mi, n = nq * 2 + ni;
          acc[m][n] = mfma16(af[mi][0], bf[ni][0], acc[m][n]);
          acc[m][n] = mfma16(af[mi][1], bf[ni][1], acc[m][n]);
        }
      __builtin_amdgcn_s_setprio(0);
      if (p < 3) __builtin_amdgcn_s_barrier();
    }
    __syncthreads();  // tile boundary: drains next tile's loads + LDS reads
  }

#pragma unroll
  for (int m = 0; m < 8; ++m)
#pragma unroll
    for (int n = 0; n < 4; ++n) {
      int col = col0 + wn * 64 + n * 16 + lo;
#pragma unroll
      for (int j = 0; j < 4; ++j) {
        int row = row0 + wm * 128 + m * 16 + hi * 4 + j;
        float v = acc[m][n][j];
        if (BIAS) v += bias[col];
        if (CF32) ((float*)Cp)[(size_t)row * N + col] = v;
        else ((unsigned short*)Cp)[(size_t)row * N + col] = f2bf(v);
      }
    }
}

// ---------------------------------------------------------------------------
// reg-staged GEMM for small fp32-A cases (M guarded): K/V projections.
// ---------------------------------------------------------------------------
__launch_bounds__(256)
__global__ void gemm_small_f32a(const float* __restrict__ Ap, const unsigned short* __restrict__ Bt,
                                unsigned short* __restrict__ Cp, int M, int N, int K) {
  __shared__ unsigned short As[128][40];
  __shared__ unsigned short Bs[128][40];
  int bn = blockIdx.x, bm = blockIdx.y;
  int tid = threadIdx.x;
  int l = tid & 63, wid = tid >> 6, lo = l & 15, hi = l >> 4;
  int wm = wid >> 1, wn = wid & 1;
  f32x4 z = {0.0f, 0.0f, 0.0f, 0.0f};
  f32x4 acc[4][4];
#pragma unroll
  for (int m = 0; m < 4; ++m)
#pragma unroll
    for (int n = 0; n < 4; ++n) acc[m][n] = z;
  int row0 = bm * 128;
  int ar = tid >> 2, acg = tid & 3;
  int bnr = tid >> 1, bhf = tid & 1;

  for (int k0 = 0; k0 < K; k0 += 32) {
    __syncthreads();
#pragma unroll
    for (int rr = 0; rr < 2; ++rr) {
      int row = ar + rr * 64;
      int grow = row0 + row;
      short8 v = {0, 0, 0, 0, 0, 0, 0, 0};
      if (grow < M) {
        const float* ap = Ap + (size_t)grow * K + k0 + acg * 8;
        f32x4 v0 = *(const f32x4*)ap;
        f32x4 v1 = *(const f32x4*)(ap + 4);
        v[0] = (short)f2bf(v0[0]); v[1] = (short)f2bf(v0[1]);
        v[2] = (short)f2bf(v0[2]); v[3] = (short)f2bf(v0[3]);
        v[4] = (short)f2bf(v1[0]); v[5] = (short)f2bf(v1[1]);
        v[6] = (short)f2bf(v1[2]); v[7] = (short)f2bf(v1[3]);
      }
      *(short8*)&As[row][acg * 8] = v;
    }
    {
      const unsigned short* bp = Bt + (size_t)(bn * 128 + bnr) * K + k0 + bhf * 16;
      *(short8*)&Bs[bnr][bhf * 16] = *(const short8*)bp;
      *(short8*)&Bs[bnr][bhf * 16 + 8] = *(const short8*)(bp + 8);
    }
    __syncthreads();
    short8 af[4], bf[4];
#pragma unroll
    for (int m = 0; m < 4; ++m) af[m] = *(const short8*)&As[wm * 64 + m * 16 + lo][hi * 8];
#pragma unroll
    for (int n = 0; n < 4; ++n) bf[n] = *(const short8*)&Bs[wn * 64 + n * 16 + lo][hi * 8];
#pragma unroll
    for (int m = 0; m < 4; ++m)
#pragma unroll
      for (int n = 0; n < 4; ++n) acc[m][n] = mfma16(af[m], bf[n], acc[m][n]);
  }

#pragma unroll
  for (int m = 0; m < 4; ++m)
#pragma unroll
    for (int n = 0; n < 4; ++n) {
      int col = bn * 128 + wn * 64 + n * 16 + lo;
#pragma unroll
      for (int j = 0; j < 4; ++j) {
        int row = row0 + wm * 64 + m * 16 + hi * 4 + j;
        if (row < M) Cp[(size_t)row * N + col] = f2bf(acc[m][n][j]);
      }
    }
}

// ---------------------------------------------------------------------------
// Attention: Sk=77 single tile. Q/K read straight from global (L2-fit);
// only V^T and P go through LDS.
// ---------------------------------------------------------------------------
#define QB 64
__launch_bounds__(256)
__global__ void attn_kernel(const unsigned short* __restrict__ Q,
                            const unsigned short* __restrict__ Kp,
                            const unsigned short* __restrict__ Vp,
                            unsigned short* __restrict__ O) {
  __shared__ alignas(16) unsigned short Vt[160][104];
  __shared__ alignas(16) unsigned short Ps[QB][104];
  int tile = blockIdx.x, bh = blockIdx.y;
  int b = bh >> 3, h = bh & 7;
  int tid = threadIdx.x;

  const unsigned short* Vb = Vp + (size_t)(b * 77) * 1280 + h * 160;
  for (int cid = tid; cid < 77 * 20; cid += 256) {
    int t = cid / 20, c = cid - t * 20;
    short8 v = *(const short8*)&Vb[(size_t)t * 1280 + c * 8];
#pragma unroll
    for (int j = 0; j < 8; ++j) Vt[c * 8 + j][t] = (unsigned short)v[j];
  }
  for (int cid = tid; cid < 160 * 27; cid += 256) {
    int d = cid / 27, t = 77 + (cid - d * 27);
    Vt[d][t] = 0;
  }
  for (int cid = tid; cid < QB * 16; cid += 256) {
    int r = cid / 16, c = 80 + (cid & 15);
    Ps[r][c] = 0;
  }

  int l = tid & 63, wid = tid >> 6, lo = l & 15, hi = l >> 4;

  const unsigned short* qrow =
      Q + (size_t)(b * 4096 + tile * QB + wid * 16 + lo) * 1280 + h * 160;
  short8 a[5];
#pragma unroll
  for (int kt = 0; kt < 5; ++kt) a[kt] = *(const short8*)&qrow[kt * 32 + hi * 8];

  const unsigned short* Kb = Kp + (size_t)(b * 77) * 1280 + h * 160;
  f32x4 z = {0.0f, 0.0f, 0.0f, 0.0f};
  f32x4 sc[5];
#pragma unroll
  for (int n = 0; n < 5; ++n) sc[n] = z;
#pragma unroll
  for (int n = 0; n < 5; ++n) {
    const unsigned short* krow = Kb + (size_t)(n * 16 + lo) * 1280;
#pragma unroll
    for (int kt = 0; kt < 5; ++kt) {
      short8 bb = *(const short8*)&krow[kt * 32 + hi * 8];
      sc[n] = mfma16(a[kt], bb, sc[n]);
    }
  }
  if (lo >= 13) { sc[4][0] = -1e30f; sc[4][1] = -1e30f; sc[4][2] = -1e30f; sc[4][3] = -1e30f; }

  float pinv[4];
#pragma unroll
  for (int j = 0; j < 4; ++j) {
    float mx = sc[0][j];
#pragma unroll
    for (int n = 1; n < 5; ++n) mx = fmaxf(mx, sc[n][j]);
#pragma unroll
    for (int msk = 1; msk < 16; msk <<= 1) mx = fmaxf(mx, __shfl_xor(mx, msk, 64));
    float s = 0.0f;
#pragma unroll
    for (int n = 0; n < 5; ++n) {
      float p = __expf(sc[n][j] - mx);
      sc[n][j] = p;
      s += p;
    }
#pragma unroll
    for (int msk = 1; msk < 16; msk <<= 1) s += __shfl_xor(s, msk, 64);
    pinv[j] = 1.0f / s;
  }
#pragma unroll
  for (int n = 0; n < 5; ++n)
#pragma unroll
    for (int j = 0; j < 4; ++j)
      Ps[wid * 16 + hi * 4 + j][n * 16 + lo] = f2bf(sc[n][j] * pinv[j]);
  __syncthreads();

  f32x4 o[10];
#pragma unroll
  for (int n = 0; n < 10; ++n) o[n] = z;
#pragma unroll
  for (int kt = 0; kt < 3; ++kt) {
    short8 pa = *(const short8*)&Ps[wid * 16 + lo][kt * 32 + hi * 8];
#pragma unroll
    for (int n = 0; n < 10; ++n) {
      short8 vb = *(const short8*)&Vt[n * 16 + lo][kt * 32 + hi * 8];
      o[n] = mfma16(pa, vb, o[n]);
    }
  }
  unsigned short* Ob = O + (size_t)(b * 4096 + tile * QB + wid * 16 + hi * 4) * 1280 + h * 160;
#pragma unroll
  for (int n = 0; n < 10; ++n)
#pragma unroll
    for (int j = 0; j < 4; ++j)
      Ob[(size_t)j * 1280 + n * 16 + lo] = f2bf(o[n][j]);
}

// ---------------------------------------------------------------------------
extern "C" void kernel_launch(void* const* d_in, const int* in_sizes, int n_in,
                              void* d_out, int out_size, void* d_ws, size_t ws_size,
                              hipStream_t stream) {
  const float* hidden   = (const float*)d_in[0];
  const float* enc      = (const float*)d_in[1];
  const float* Pq_in    = (const float*)d_in[2];
  const float* Pk_in    = (const float*)d_in[3];
  const float* Pv_in    = (const float*)d_in[4];
  const float* Pout_in  = (const float*)d_in[5];
  const float* Pq_out   = (const float*)d_in[6];
  const float* Pk_out   = (const float*)d_in[7];
  const float* Pv_out   = (const float*)d_in[8];
  const float* Pout_out = (const float*)d_in[9];
  const float* Wq       = (const float*)d_in[10];
  const float* Wk       = (const float*)d_in[11];
  const float* Wv       = (const float*)d_in[12];
  const float* Wout     = (const float*)d_in[13];
  const float* bout     = (const float*)d_in[14];
  const float* q_scale  = (const float*)d_in[15];
  const float* k_scale  = (const float*)d_in[16];
  const float* v_scale  = (const float*)d_in[17];
  const float* out_scale= (const float*)d_in[18];

  char* w = (char*)d_ws;
  unsigned short* attnO = (unsigned short*)w; w += 32768LL * 1280 * 2;
  unsigned short* WqT   = (unsigned short*)w; w += 1280LL * 1280 * 2;
  unsigned short* WkT   = (unsigned short*)w; w += 1280LL * 768 * 2;
  unsigned short* WvT   = (unsigned short*)w; w += 1280LL * 768 * 2;
  unsigned short* WoT   = (unsigned short*)w; w += 1280LL * 1280 * 2;
  unsigned short* Kbf   = (unsigned short*)w; w += 616LL * 1280 * 2;
  unsigned short* Vbf   = (unsigned short*)w; w += 616LL * 1280 * 2;
  float* cQq_in   = (float*)w; w += 16LL * 80 * 80 * 4;
  float* cQout_in = (float*)w; w += 16LL * 80 * 80 * 4;
  float* cQq_out  = (float*)w; w += 16LL * 80 * 80 * 4;
  float* cQk_out  = (float*)w; w += 16LL * 80 * 80 * 4;
  float* cQv_out  = (float*)w; w += 16LL * 80 * 80 * 4;
  float* cQout_out= (float*)w; w += 16LL * 80 * 80 * 4;
  float* cQk_in   = (float*)w; w += 16LL * 48 * 48 * 4;
  float* cQv_in   = (float*)w; w += 16LL * 48 * 48 * 4;

  unsigned short* Xbf = (unsigned short*)d_out;
  unsigned short* Qbf = Xbf + 32768LL * 1280;

  CayleyPtrs cp;
  cp.P[0] = Pq_in;    cp.Q[0] = cQq_in;
  cp.P[1] = Pout_in;  cp.Q[1] = cQout_in;
  cp.P[2] = Pq_out;   cp.Q[2] = cQq_out;
  cp.P[3] = Pk_out;   cp.Q[3] = cQk_out;
  cp.P[4] = Pv_out;   cp.Q[4] = cQv_out;
  cp.P[5] = Pout_out; cp.Q[5] = cQout_out;
  cp.P[6] = Pk_in;    cp.Q[6] = cQk_in;
  cp.P[7] = Pv_in;    cp.Q[7] = cQv_in;
  cayley_all<<<128, 256, 0, stream>>>(cp);

  const float ATTN_SCALE = 0.07905694150420949f;  // 160^-0.5
  BuildArgs ba;
  ba.Qin[0] = cQq_in;   ba.W[0] = Wq;   ba.Qout[0] = cQq_out;   ba.scale[0] = q_scale;
  ba.WeffT[0] = WqT;    ba.extra[0] = ATTN_SCALE; ba.b[0] = 80; ba.Kin[0] = 1280;
  ba.Qin[1] = cQk_in;   ba.W[1] = Wk;   ba.Qout[1] = cQk_out;   ba.scale[1] = k_scale;
  ba.WeffT[1] = WkT;    ba.extra[1] = 1.0f;       ba.b[1] = 48; ba.Kin[1] = 768;
  ba.Qin[2] = cQv_in;   ba.W[2] = Wv;   ba.Qout[2] = cQv_out;   ba.scale[2] = v_scale;
  ba.WeffT[2] = WvT;    ba.extra[2] = 1.0f;       ba.b[2] = 48; ba.Kin[2] = 768;
  ba.Qin[3] = cQout_in; ba.W[3] = Wout; ba.Qout[3] = cQout_out; ba.scale[3] = out_scale;
  ba.WeffT[3] = WoT;    ba.extra[3] = 1.0f;       ba.b[3] = 80; ba.Kin[3] = 1280;
  build_all<<<dim3(16, 16, 4), 256, 0, stream>>>(ba);

  f32_to_bf16_kernel<<<2048, 256, 0, stream>>>(hidden, Xbf, 32768LL * 1280);

  // Q = Xbf @ WqT^T   (640 blocks of 512 threads, XCD-swizzled, 8-phase)
  gemm256<false, false><<<640, 512, 0, stream>>>(Xbf, WqT, Qbf, nullptr, 32768, 1280, 1280);
  gemm_small_f32a<<<dim3(10, 5), 256, 0, stream>>>(enc, WkT, Kbf, 616, 1280, 768);
  gemm_small_f32a<<<dim3(10, 5), 256, 0, stream>>>(enc, WvT, Vbf, 616, 1280, 768);

  attn_kernel<<<dim3(64, 64), 256, 0, stream>>>(Qbf, Kbf, Vbf, attnO);

  gemm256<true, true><<<640, 512, 0, stream>>>(attnO, WoT, d_out, bout, 32768, 1280, 1280);
}

// Round 6
// 686.037 us; speedup vs baseline: 4.0697x; 1.0013x over previous
//
#include <hip/hip_runtime.h>

typedef __attribute__((ext_vector_type(4))) float f32x4;
typedef __attribute__((ext_vector_type(8))) short short8;
typedef __attribute__((ext_vector_type(8))) __bf16 bf16x8;
typedef __attribute__((ext_vector_type(4))) unsigned short us4;

__device__ __forceinline__ unsigned short f2bf(float f) {
  unsigned u = __builtin_bit_cast(unsigned, f);
  u = (u + 0x7FFFu + ((u >> 16) & 1u)) >> 16;
  return (unsigned short)u;
}

__device__ __forceinline__ f32x4 mfma16(short8 a, short8 b, f32x4 c) {
  return __builtin_amdgcn_mfma_f32_16x16x32_bf16(
      __builtin_bit_cast(bf16x8, a), __builtin_bit_cast(bf16x8, b), c, 0, 0, 0);
}

// async global->LDS, 16B per lane. LDS dest must be wave-uniform base; HW adds lane*16.
__device__ __forceinline__ void gload16(const unsigned short* g, unsigned short* l) {
  __builtin_amdgcn_global_load_lds((const __attribute__((address_space(1))) void*)g,
                                   (__attribute__((address_space(3))) void*)l, 16, 0, 0);
}

__device__ __forceinline__ float dot4(f32x4 x, f32x4 y) {
  return x[0] * y[0] + x[1] * y[1] + x[2] * y[2] + x[3] * y[3];
}

// ---------------------------------------------------------------------------
// Fused Cayley for all 8 parameter tensors in ONE launch (128 blocks).
// ---------------------------------------------------------------------------
struct CayleyPtrs {
  const float* P[8];
  float* Q[8];
};

__launch_bounds__(256)
__global__ void cayley_all(CayleyPtrs ptrs) {
  __shared__ float M[80 * 80];
  __shared__ float R[80 * 80];
  __shared__ float fcol[80];
  int t = blockIdx.x >> 4, g = blockIdx.x & 15;
  int n = (t < 6) ? 80 : 48;
  int tid = threadIdx.x;
  const float* Pg = ptrs.P[t] + (size_t)g * n * n;
  float* Qg = ptrs.Q[t] + (size_t)g * n * n;

  for (int idx = tid; idx < n * n; idx += 256) {
    int i = idx / n, j = idx - i * n;
    float a = Pg[i * n + j] - Pg[j * n + i];
    float id = (i == j) ? 1.0f : 0.0f;
    M[idx] = id - a;
    R[idx] = id + a;
  }
  __syncthreads();

  int nch = n >> 2;
  int tot = n * nch;
  for (int k = 0; k < n; ++k) {
    if (tid < n) {
      float inv = 1.0f / M[k * n + k];
      fcol[tid] = (tid == k) ? 0.0f : M[tid * n + k] * inv;
    }
    __syncthreads();
    for (int idx = tid; idx < tot; idx += 256) {
      int i = idx / nch, c = idx - i * nch;
      float f = fcol[i];
      ((f32x4*)&R[i * n])[c] = ((f32x4*)&R[i * n])[c] - f * ((const f32x4*)&R[k * n])[c];
    }
    int c0 = k >> 2, mw = nch - c0, totM = n * mw;
    for (int idx = tid; idx < totM; idx += 256) {
      int i = idx / mw, c = c0 + idx - i * mw;
      float f = fcol[i];
      ((f32x4*)&M[i * n])[c] = ((f32x4*)&M[i * n])[c] - f * ((const f32x4*)&M[k * n])[c];
    }
    __syncthreads();
  }
  for (int idx = tid; idx < n * n; idx += 256) {
    int i = idx / n;
    Qg[idx] = R[idx] / M[i * n + i];
  }
}

// ---------------------------------------------------------------------------
// Fused effective weights, all 4 tensors: grid (16,16,4). 4x4 reg blocking.
// ---------------------------------------------------------------------------
struct BuildArgs {
  const float* Qin[4];
  const float* W[4];
  const float* Qout[4];
  const float* scale[4];
  unsigned short* WeffT[4];
  float extra[4];
  int b[4];
  int Kin[4];
};

#define BS 84  // LDS row stride in floats

__launch_bounds__(256)
__global__ void build_all(BuildArgs A) {
  __shared__ float Qs[80 * BS];
  __shared__ float Ws[80 * BS];
  __shared__ float T1[80 * BS];
  int z = blockIdx.z;
  int gi = blockIdx.x, go = blockIdx.y, tid = threadIdx.x;
  int b = A.b[z], Kin = A.Kin[z];
  float extra = A.extra[z];
  const float* Qin = A.Qin[z];
  const float* W = A.W[z];
  const float* Qout = A.Qout[z];
  const float* scale = A.scale[z];
  unsigned short* WeffT = A.WeffT[z];

  for (int idx = tid; idx < b * b; idx += 256) {
    int i = idx / b, j = idx - i * b;
    Qs[i * BS + j] = Qin[(size_t)gi * b * b + idx];
  }
  for (int idx = tid; idx < 80 * b; idx += 256) {
    int m = idx / b, j = idx - m * b;
    Ws[m * BS + j] = W[(size_t)(go * 80 + m) * Kin + gi * b + j];
  }
  __syncthreads();

  int itiles = b >> 2;
  int jch = b >> 2;
  int NT = itiles * 20;
  for (int t = tid; t < NT; t += 256) {
    int ti = t / 20, tm = t - ti * 20;
    float acc[4][4] = {};
    for (int jc = 0; jc < jch; ++jc) {
      f32x4 qa[4], wb[4];
#pragma unroll
      for (int p = 0; p < 4; ++p) qa[p] = *(const f32x4*)&Qs[(4 * ti + p) * BS + jc * 4];
#pragma unroll
      for (int p = 0; p < 4; ++p) wb[p] = *(const f32x4*)&Ws[(4 * tm + p) * BS + jc * 4];
#pragma unroll
      for (int p = 0; p < 4; ++p)
#pragma unroll
        for (int q = 0; q < 4; ++q) acc[p][q] += dot4(qa[p], wb[q]);
    }
#pragma unroll
    for (int p = 0; p < 4; ++p)
#pragma unroll
      for (int q = 0; q < 4; ++q) T1[(4 * ti + p) * BS + 4 * tm + q] = acc[p][q];
  }
  __syncthreads();
  for (int idx = tid; idx < 6400; idx += 256) {
    int m = idx / 80, n = idx - m * 80;
    Qs[n * BS + m] = Qout[(size_t)go * 6400 + idx];
  }
  __syncthreads();
  for (int t = tid; t < NT; t += 256) {
    int ti = t / 20, tn = t - ti * 20;
    float acc[4][4] = {};
    for (int mc = 0; mc < 20; ++mc) {
      f32x4 ta[4], qb[4];
#pragma unroll
      for (int p = 0; p < 4; ++p) ta[p] = *(const f32x4*)&T1[(4 * ti + p) * BS + mc * 4];
#pragma unroll
      for (int p = 0; p < 4; ++p) qb[p] = *(const f32x4*)&Qs[(4 * tn + p) * BS + mc * 4];
#pragma unroll
      for (int p = 0; p < 4; ++p)
#pragma unroll
        for (int q = 0; q < 4; ++q) acc[p][q] += dot4(ta[p], qb[q]);
    }
#pragma unroll
    for (int q = 0; q < 4; ++q) {
      int col = go * 80 + 4 * tn + q;
      float sc = scale[col] * extra;
#pragma unroll
      for (int p = 0; p < 4; ++p)
        WeffT[(size_t)col * Kin + gi * b + 4 * ti + p] = f2bf(acc[p][q] * sc);
    }
  }
}

// ---------------------------------------------------------------------------
// fp32 -> bf16 bulk convert
// ---------------------------------------------------------------------------
__launch_bounds__(256)
__global__ void f32_to_bf16_kernel(const float* __restrict__ in, unsigned short* __restrict__ out,
                                   long long n) {
  long long i = ((long long)blockIdx.x * 256 + threadIdx.x) * 4;
  long long stride = (long long)gridDim.x * 256 * 4;
  for (; i < n; i += stride) {
    f32x4 v = *(const f32x4*)(in + i);
    us4 o;
    o[0] = f2bf(v[0]); o[1] = f2bf(v[1]); o[2] = f2bf(v[2]); o[3] = f2bf(v[3]);
    *(us4*)(out + i) = o;
  }
}

// ---------------------------------------------------------------------------
// 256x256 bf16 MFMA GEMM, fragment-reuse schedule: C[M,N] = A[M,K] @ Bt[N,K]^T.
// BK=64, 512 threads (8 waves, 2Mx4N, 128x64 out/wave), double-buffered 128KB
// linear LDS via global_load_lds w=16 with XOR slot-swizzle (both-sides).
// Per K-tile per wave: 8 bf reads ONCE + 4 m-pair phases {4 af reads, 16 MFMA}
// = 24 ds_read_b128 (min for this tiling), one __syncthreads per K-tile.
// Prefetch for tile t+1 issued at start of tile t (drained by tile-end barrier).
// Requires M%256==0, N%256==0, K%64==0, grid % 8 == 0.
// ---------------------------------------------------------------------------
template <bool CF32, bool BIAS>
__launch_bounds__(512, 2)
__global__ void gemm256(const unsigned short* __restrict__ A,
                        const unsigned short* __restrict__ Bt,
                        void* __restrict__ Cp, const float* __restrict__ bias,
                        int M, int N, int K) {
  __shared__ alignas(128) unsigned short AsL[2][256 * 64];
  __shared__ alignas(128) unsigned short BsL[2][256 * 64];
  int per = gridDim.x >> 3;
  int bid = blockIdx.x;
  int nid = (bid & 7) * per + (bid >> 3);
  int nbn = N >> 8;
  int bm = nid / nbn, bn = nid - bm * nbn;
  int row0 = bm << 8, col0 = bn << 8;

  int tid = threadIdx.x;
  int w = tid >> 6, l = tid & 63, lo = l & 15, hi = l >> 4;
  int wm = w >> 2, wn = w & 3;
  int rsw = lo & 7;

  // staging: wave w covers rows [w*32, +32), 4 issues of 8 rows each (A and B).
  // LDS slot s of row r holds global chunk s^(r&7)  (involution swizzle).
  int sr8 = l >> 3;
  int chunk = (l & 7) ^ sr8;
  const unsigned short* Ag = A + (size_t)(row0 + w * 32 + sr8) * K + chunk * 8;
  const unsigned short* Bg = Bt + (size_t)(col0 + w * 32 + sr8) * K + chunk * 8;

  int NT = K >> 6;

  f32x4 z = {0.0f, 0.0f, 0.0f, 0.0f};
  f32x4 acc[8][4];
#pragma unroll
  for (int m = 0; m < 8; ++m)
#pragma unroll
    for (int n = 0; n < 4; ++n) acc[m][n] = z;

  auto stage = [&](int t, int X) {
    const unsigned short* ag = Ag + t * 64;
    const unsigned short* bg = Bg + t * 64;
    unsigned short* la = &AsL[X][w * 2048];
    unsigned short* lb = &BsL[X][w * 2048];
#pragma unroll
    for (int i = 0; i < 4; ++i) {
      gload16(ag + (size_t)(i * 8) * K, la + i * 512);
      gload16(bg + (size_t)(i * 8) * K, lb + i * 512);
    }
  };

  stage(0, 0);
  __syncthreads();  // drains vmcnt(0): tile 0 landed

  for (int t = 0; t < NT; ++t) {
    int X = t & 1;
    const unsigned short* cA = &AsL[X][0];
    const unsigned short* cB = &BsL[X][0];
    if (t + 1 < NT) stage(t + 1, X ^ 1);  // issue-early prefetch (one tile of compute to hide)

    // load ALL B fragments once (8 ds_read_b128)
    short8 bf[4][2];
#pragma unroll
    for (int ni = 0; ni < 4; ++ni) {
      int col = wn * 64 + ni * 16 + lo;
#pragma unroll
      for (int kk = 0; kk < 2; ++kk)
        bf[ni][kk] = *(const short8*)&cB[col * 64 + ((kk * 4 + hi) ^ rsw) * 8];
    }
    // 4 m-pair phases: {4 af reads, 16 MFMA}
#pragma unroll
    for (int mp = 0; mp < 4; ++mp) {
      short8 af[2][2];
#pragma unroll
      for (int mi = 0; mi < 2; ++mi) {
        int row = wm * 128 + (mp * 2 + mi) * 16 + lo;
#pragma unroll
        for (int kk = 0; kk < 2; ++kk)
          af[mi][kk] = *(const short8*)&cA[row * 64 + ((kk * 4 + hi) ^ rsw) * 8];
      }
      __builtin_amdgcn_s_setprio(1);
#pragma unroll
      for (int mi = 0; mi < 2; ++mi)
#pragma unroll
        for (int ni = 0; ni < 4; ++ni) {
          int m = mp * 2 + mi;
          acc[m][ni] = mfma16(af[mi][0], bf[ni][0], acc[m][ni]);
          acc[m][ni] = mfma16(af[mi][1], bf[ni][1], acc[m][ni]);
        }
      __builtin_amdgcn_s_setprio(0);
    }
    __syncthreads();  // tile boundary: drains prefetch loads; all reads of X done
  }

#pragma unroll
  for (int m = 0; m < 8; ++m)
#pragma unroll
    for (int n = 0; n < 4; ++n) {
      int col = col0 + wn * 64 + n * 16 + lo;
#pragma unroll
      for (int j = 0; j < 4; ++j) {
        int row = row0 + wm * 128 + m * 16 + hi * 4 + j;
        float v = acc[m][n][j];
        if (BIAS) v += bias[col];
        if (CF32) ((float*)Cp)[(size_t)row * N + col] = v;
        else ((unsigned short*)Cp)[(size_t)row * N + col] = f2bf(v);
      }
    }
}

// ---------------------------------------------------------------------------
// reg-staged GEMM for small fp32-A cases (M guarded): K/V projections.
// ---------------------------------------------------------------------------
__launch_bounds__(256)
__global__ void gemm_small_f32a(const float* __restrict__ Ap, const unsigned short* __restrict__ Bt,
                                unsigned short* __restrict__ Cp, int M, int N, int K) {
  __shared__ unsigned short As[128][40];
  __shared__ unsigned short Bs[128][40];
  int bn = blockIdx.x, bm = blockIdx.y;
  int tid = threadIdx.x;
  int l = tid & 63, wid = tid >> 6, lo = l & 15, hi = l >> 4;
  int wm = wid >> 1, wn = wid & 1;
  f32x4 z = {0.0f, 0.0f, 0.0f, 0.0f};
  f32x4 acc[4][4];
#pragma unroll
  for (int m = 0; m < 4; ++m)
#pragma unroll
    for (int n = 0; n < 4; ++n) acc[m][n] = z;
  int row0 = bm * 128;
  int ar = tid >> 2, acg = tid & 3;
  int bnr = tid >> 1, bhf = tid & 1;

  for (int k0 = 0; k0 < K; k0 += 32) {
    __syncthreads();
#pragma unroll
    for (int rr = 0; rr < 2; ++rr) {
      int row = ar + rr * 64;
      int grow = row0 + row;
      short8 v = {0, 0, 0, 0, 0, 0, 0, 0};
      if (grow < M) {
        const float* ap = Ap + (size_t)grow * K + k0 + acg * 8;
        f32x4 v0 = *(const f32x4*)ap;
        f32x4 v1 = *(const f32x4*)(ap + 4);
        v[0] = (short)f2bf(v0[0]); v[1] = (short)f2bf(v0[1]);
        v[2] = (short)f2bf(v0[2]); v[3] = (short)f2bf(v0[3]);
        v[4] = (short)f2bf(v1[0]); v[5] = (short)f2bf(v1[1]);
        v[6] = (short)f2bf(v1[2]); v[7] = (short)f2bf(v1[3]);
      }
      *(short8*)&As[row][acg * 8] = v;
    }
    {
      const unsigned short* bp = Bt + (size_t)(bn * 128 + bnr) * K + k0 + bhf * 16;
      *(short8*)&Bs[bnr][bhf * 16] = *(const short8*)bp;
      *(short8*)&Bs[bnr][bhf * 16 + 8] = *(const short8*)(bp + 8);
    }
    __syncthreads();
    short8 af[4], bf[4];
#pragma unroll
    for (int m = 0; m < 4; ++m) af[m] = *(const short8*)&As[wm * 64 + m * 16 + lo][hi * 8];
#pragma unroll
    for (int n = 0; n < 4; ++n) bf[n] = *(const short8*)&Bs[wn * 64 + n * 16 + lo][hi * 8];
#pragma unroll
    for (int m = 0; m < 4; ++m)
#pragma unroll
      for (int n = 0; n < 4; ++n) acc[m][n] = mfma16(af[m], bf[n], acc[m][n]);
  }

#pragma unroll
  for (int m = 0; m < 4; ++m)
#pragma unroll
    for (int n = 0; n < 4; ++n) {
      int col = bn * 128 + wn * 64 + n * 16 + lo;
#pragma unroll
      for (int j = 0; j < 4; ++j) {
        int row = row0 + wm * 64 + m * 16 + hi * 4 + j;
        if (row < M) Cp[(size_t)row * N + col] = f2bf(acc[m][n][j]);
      }
    }
}

// ---------------------------------------------------------------------------
// Attention: Sk=77 single tile. Q/K read straight from global (L2-fit);
// only V^T and P go through LDS.
// ---------------------------------------------------------------------------
#define QB 64
__launch_bounds__(256)
__global__ void attn_kernel(const unsigned short* __restrict__ Q,
                            const unsigned short* __restrict__ Kp,
                            const unsigned short* __restrict__ Vp,
                            unsigned short* __restrict__ O) {
  __shared__ alignas(16) unsigned short Vt[160][104];
  __shared__ alignas(16) unsigned short Ps[QB][104];
  int tile = blockIdx.x, bh = blockIdx.y;
  int b = bh >> 3, h = bh & 7;
  int tid = threadIdx.x;

  const unsigned short* Vb = Vp + (size_t)(b * 77) * 1280 + h * 160;
  for (int cid = tid; cid < 77 * 20; cid += 256) {
    int t = cid / 20, c = cid - t * 20;
    short8 v = *(const short8*)&Vb[(size_t)t * 1280 + c * 8];
#pragma unroll
    for (int j = 0; j < 8; ++j) Vt[c * 8 + j][t] = (unsigned short)v[j];
  }
  for (int cid = tid; cid < 160 * 27; cid += 256) {
    int d = cid / 27, t = 77 + (cid - d * 27);
    Vt[d][t] = 0;
  }
  for (int cid = tid; cid < QB * 16; cid += 256) {
    int r = cid / 16, c = 80 + (cid & 15);
    Ps[r][c] = 0;
  }

  int l = tid & 63, wid = tid >> 6, lo = l & 15, hi = l >> 4;

  const unsigned short* qrow =
      Q + (size_t)(b * 4096 + tile * QB + wid * 16 + lo) * 1280 + h * 160;
  short8 a[5];
#pragma unroll
  for (int kt = 0; kt < 5; ++kt) a[kt] = *(const short8*)&qrow[kt * 32 + hi * 8];

  const unsigned short* Kb = Kp + (size_t)(b * 77) * 1280 + h * 160;
  f32x4 z = {0.0f, 0.0f, 0.0f, 0.0f};
  f32x4 sc[5];
#pragma unroll
  for (int n = 0; n < 5; ++n) sc[n] = z;
#pragma unroll
  for (int n = 0; n < 5; ++n) {
    const unsigned short* krow = Kb + (size_t)(n * 16 + lo) * 1280;
#pragma unroll
    for (int kt = 0; kt < 5; ++kt) {
      short8 bb = *(const short8*)&krow[kt * 32 + hi * 8];
      sc[n] = mfma16(a[kt], bb, sc[n]);
    }
  }
  if (lo >= 13) { sc[4][0] = -1e30f; sc[4][1] = -1e30f; sc[4][2] = -1e30f; sc[4][3] = -1e30f; }

  float pinv[4];
#pragma unroll
  for (int j = 0; j < 4; ++j) {
    float mx = sc[0][j];
#pragma unroll
    for (int n = 1; n < 5; ++n) mx = fmaxf(mx, sc[n][j]);
#pragma unroll
    for (int msk = 1; msk < 16; msk <<= 1) mx = fmaxf(mx, __shfl_xor(mx, msk, 64));
    float s = 0.0f;
#pragma unroll
    for (int n = 0; n < 5; ++n) {
      float p = __expf(sc[n][j] - mx);
      sc[n][j] = p;
      s += p;
    }
#pragma unroll
    for (int msk = 1; msk < 16; msk <<= 1) s += __shfl_xor(s, msk, 64);
    pinv[j] = 1.0f / s;
  }
#pragma unroll
  for (int n = 0; n < 5; ++n)
#pragma unroll
    for (int j = 0; j < 4; ++j)
      Ps[wid * 16 + hi * 4 + j][n * 16 + lo] = f2bf(sc[n][j] * pinv[j]);
  __syncthreads();

  f32x4 o[10];
#pragma unroll
  for (int n = 0; n < 10; ++n) o[n] = z;
#pragma unroll
  for (int kt = 0; kt < 3; ++kt) {
    short8 pa = *(const short8*)&Ps[wid * 16 + lo][kt * 32 + hi * 8];
#pragma unroll
    for (int n = 0; n < 10; ++n) {
      short8 vb = *(const short8*)&Vt[n * 16 + lo][kt * 32 + hi * 8];
      o[n] = mfma16(pa, vb, o[n]);
    }
  }
  unsigned short* Ob = O + (size_t)(b * 4096 + tile * QB + wid * 16 + hi * 4) * 1280 + h * 160;
#pragma unroll
  for (int n = 0; n < 10; ++n)
#pragma unroll
    for (int j = 0; j < 4; ++j)
      Ob[(size_t)j * 1280 + n * 16 + lo] = f2bf(o[n][j]);
}

// ---------------------------------------------------------------------------
extern "C" void kernel_launch(void* const* d_in, const int* in_sizes, int n_in,
                              void* d_out, int out_size, void* d_ws, size_t ws_size,
                              hipStream_t stream) {
  const float* hidden   = (const float*)d_in[0];
  const float* enc      = (const float*)d_in[1];
  const float* Pq_in    = (const float*)d_in[2];
  const float* Pk_in    = (const float*)d_in[3];
  const float* Pv_in    = (const float*)d_in[4];
  const float* Pout_in  = (const float*)d_in[5];
  const float* Pq_out   = (const float*)d_in[6];
  const float* Pk_out   = (const float*)d_in[7];
  const float* Pv_out   = (const float*)d_in[8];
  const float* Pout_out = (const float*)d_in[9];
  const float* Wq       = (const float*)d_in[10];
  const float* Wk       = (const float*)d_in[11];
  const float* Wv       = (const float*)d_in[12];
  const float* Wout     = (const float*)d_in[13];
  const float* bout     = (const float*)d_in[14];
  const float* q_scale  = (const float*)d_in[15];
  const float* k_scale  = (const float*)d_in[16];
  const float* v_scale  = (const float*)d_in[17];
  const float* out_scale= (const float*)d_in[18];

  char* w = (char*)d_ws;
  unsigned short* attnO = (unsigned short*)w; w += 32768LL * 1280 * 2;
  unsigned short* WqT   = (unsigned short*)w; w += 1280LL * 1280 * 2;
  unsigned short* WkT   = (unsigned short*)w; w += 1280LL * 768 * 2;
  unsigned short* WvT   = (unsigned short*)w; w += 1280LL * 768 * 2;
  unsigned short* WoT   = (unsigned short*)w; w += 1280LL * 1280 * 2;
  unsigned short* Kbf   = (unsigned short*)w; w += 616LL * 1280 * 2;
  unsigned short* Vbf   = (unsigned short*)w; w += 616LL * 1280 * 2;
  float* cQq_in   = (float*)w; w += 16LL * 80 * 80 * 4;
  float* cQout_in = (float*)w; w += 16LL * 80 * 80 * 4;
  float* cQq_out  = (float*)w; w += 16LL * 80 * 80 * 4;
  float* cQk_out  = (float*)w; w += 16LL * 80 * 80 * 4;
  float* cQv_out  = (float*)w; w += 16LL * 80 * 80 * 4;
  float* cQout_out= (float*)w; w += 16LL * 80 * 80 * 4;
  float* cQk_in   = (float*)w; w += 16LL * 48 * 48 * 4;
  float* cQv_in   = (float*)w; w += 16LL * 48 * 48 * 4;

  unsigned short* Xbf = (unsigned short*)d_out;
  unsigned short* Qbf = Xbf + 32768LL * 1280;

  CayleyPtrs cp;
  cp.P[0] = Pq_in;    cp.Q[0] = cQq_in;
  cp.P[1] = Pout_in;  cp.Q[1] = cQout_in;
  cp.P[2] = Pq_out;   cp.Q[2] = cQq_out;
  cp.P[3] = Pk_out;   cp.Q[3] = cQk_out;
  cp.P[4] = Pv_out;   cp.Q[4] = cQv_out;
  cp.P[5] = Pout_out; cp.Q[5] = cQout_out;
  cp.P[6] = Pk_in;    cp.Q[6] = cQk_in;
  cp.P[7] = Pv_in;    cp.Q[7] = cQv_in;
  cayley_all<<<128, 256, 0, stream>>>(cp);

  const float ATTN_SCALE = 0.07905694150420949f;  // 160^-0.5
  BuildArgs ba;
  ba.Qin[0] = cQq_in;   ba.W[0] = Wq;   ba.Qout[0] = cQq_out;   ba.scale[0] = q_scale;
  ba.WeffT[0] = WqT;    ba.extra[0] = ATTN_SCALE; ba.b[0] = 80; ba.Kin[0] = 1280;
  ba.Qin[1] = cQk_in;   ba.W[1] = Wk;   ba.Qout[1] = cQk_out;   ba.scale[1] = k_scale;
  ba.WeffT[1] = WkT;    ba.extra[1] = 1.0f;       ba.b[1] = 48; ba.Kin[1] = 768;
  ba.Qin[2] = cQv_in;   ba.W[2] = Wv;   ba.Qout[2] = cQv_out;   ba.scale[2] = v_scale;
  ba.WeffT[2] = WvT;    ba.extra[2] = 1.0f;       ba.b[2] = 48; ba.Kin[2] = 768;
  ba.Qin[3] = cQout_in; ba.W[3] = Wout; ba.Qout[3] = cQout_out; ba.scale[3] = out_scale;
  ba.WeffT[3] = WoT;    ba.extra[3] = 1.0f;       ba.b[3] = 80; ba.Kin[3] = 1280;
  build_all<<<dim3(16, 16, 4), 256, 0, stream>>>(ba);

  f32_to_bf16_kernel<<<2048, 256, 0, stream>>>(hidden, Xbf, 32768LL * 1280);

  // Q = Xbf @ WqT^T   (640 blocks of 512 threads, XCD-swizzled)
  gemm256<false, false><<<640, 512, 0, stream>>>(Xbf, WqT, Qbf, nullptr, 32768, 1280, 1280);
  gemm_small_f32a<<<dim3(10, 5), 256, 0, stream>>>(enc, WkT, Kbf, 616, 1280, 768);
  gemm_small_f32a<<<dim3(10, 5), 256, 0, stream>>>(enc, WvT, Vbf, 616, 1280, 768);

  attn_kernel<<<dim3(64, 64), 256, 0, stream>>>(Qbf, Kbf, Vbf, attnO);

  gemm256<true, true><<<640, 512, 0, stream>>>(attnO, WoT, d_out, bout, 32768, 1280, 1280);
}